// Round 18
// baseline (327.079 us; speedup 1.0000x reference)
//
#include <hip/hip_runtime.h>

// ---------------------------------------------------------------------------
// GAMLNET GNN forward, bf16 edition, R17.
// R17 = R16 + s0->projection fusion: the s0 GEMM epilogue projects each row
// onto s1_wl/s1_wr in-register (shfl_xor reduce over lr lanes + fp32
// atomicAdd), eliminating the s0b buffer (25.6MB write + 25.6MB read) and
// the zproj dispatch entirely.
// NOTE: edge packing assumes N <= 65536 (problem fixes N=50000).
// ---------------------------------------------------------------------------

typedef unsigned short ushort_t;
typedef __bf16 bf16x8 __attribute__((ext_vector_type(8)));
typedef float f32x4 __attribute__((ext_vector_type(4)));
typedef unsigned u32x4 __attribute__((ext_vector_type(4)));

__device__ __forceinline__ float b2f(unsigned int u16) {
    union { unsigned int i; float f; } v;
    v.i = u16 << 16;
    return v.f;
}
__device__ __forceinline__ unsigned short f2b(float f) {
    union { float f; unsigned int i; } v;
    v.f = f;
    unsigned int x = v.i;
    unsigned int r = (x + 0x7fffu + ((x >> 16) & 1u)) >> 16;  // RNE
    return (unsigned short)r;
}

// async 16-byte global -> LDS copy (lane-level; LDS dest = uniform base + lane*16)
__device__ __forceinline__ void gload_lds16(const void* g, void* l) {
    __builtin_amdgcn_global_load_lds(
        (const __attribute__((address_space(1))) unsigned int*)g,
        (__attribute__((address_space(3))) unsigned int*)l,
        16, 0, 0);
}

// --- edge dtype detection: if input is int64, odd int32 words are all zero ---
__global__ void detect_kernel(const int* __restrict__ ei, int ncheck, int* flag) {
    int t = blockIdx.x * blockDim.x + threadIdx.x;
    if (t < ncheck) {
        if (ei[2 * t + 1] != 0) atomicAnd(flag, 0);
    }
}

// deg count straight from edge_index (flag-branched layout)
__global__ void deg_kernel(const int* __restrict__ ei, int E, const int* __restrict__ flag,
                           int* __restrict__ deg) {
    int e = blockIdx.x * blockDim.x + threadIdx.x;
    if (e >= E) return;
    int d = (*flag) ? ei[2 * ((size_t)E + e)] : ei[(size_t)E + e];
    atomicAdd(&deg[d], 1);
}

// --- 3-phase multi-block exclusive scan (2048 elements per block) ---
__global__ __launch_bounds__(256) void scanA_kernel(const int* __restrict__ deg, int n,
                                                    int* __restrict__ rowptr,
                                                    int* __restrict__ blocksum) {
    __shared__ int sh[256];
    int b = blockIdx.x, tid = threadIdx.x;
    int base = b * 2048 + tid * 8;
    int v[8];
#pragma unroll
    for (int e = 0; e < 8; ++e) {
        int i = base + e;
        v[e] = (i < n) ? deg[i] : 0;
    }
    int t = 0;
#pragma unroll
    for (int e = 0; e < 8; ++e) { int x = v[e]; v[e] = t; t += x; }
    sh[tid] = t;
    __syncthreads();
    for (int off = 1; off < 256; off <<= 1) {
        int val = (tid >= off) ? sh[tid - off] : 0;
        __syncthreads();
        sh[tid] += val;
        __syncthreads();
    }
    int excl = sh[tid] - t;
#pragma unroll
    for (int e = 0; e < 8; ++e) {
        int i = base + e;
        if (i < n) rowptr[i] = excl + v[e];
    }
    if (tid == 255) blocksum[b] = sh[255];
}

__global__ __launch_bounds__(256) void scanB_kernel(const int* __restrict__ blocksum, int nb,
                                                    int* __restrict__ blockoff,
                                                    int* __restrict__ rowptr, int n) {
    __shared__ int sh[256];
    int tid = threadIdx.x;
    int v = (tid < nb) ? blocksum[tid] : 0;
    sh[tid] = v;
    __syncthreads();
    for (int off = 1; off < 256; off <<= 1) {
        int t = (tid >= off) ? sh[tid - off] : 0;
        __syncthreads();
        sh[tid] += t;
        __syncthreads();
    }
    if (tid < nb) blockoff[tid] = sh[tid] - v;
    if (tid == 255) rowptr[n] = sh[255];
}

// finalize rowptr, compute invdeg/mask, and init per-bucket cursors
__global__ void scanC_kernel(const int* __restrict__ deg, int n, const int* __restrict__ blockoff,
                             int* __restrict__ rowptr, float* __restrict__ invdeg,
                             float* __restrict__ mask, int* __restrict__ bucket_cursor) {
    int i = blockIdx.x * blockDim.x + threadIdx.x;
    if (i >= n) return;
    int r = rowptr[i] + blockoff[i >> 11];
    rowptr[i] = r;
    if ((i & 255) == 0) bucket_cursor[i >> 8] = r;
    int d = deg[i];
    invdeg[i] = 1.0f / fmaxf((float)d, 1.0f);
    mask[i] = (d > 0) ? 1.0f : 0.0f;
}

// --- binned CSR phase A: LDS counting-sort of 4096-edge chunks by dst>>8,
//     parallel flush (bucket id packed in bits 24-31). ---
__global__ __launch_bounds__(256) void binA_kernel(
    const int* __restrict__ ei, int E, const int* __restrict__ flag,
    int* __restrict__ bucket_cursor, unsigned* __restrict__ stage) {
    __shared__ unsigned sPair[4096];      // 16 KB
    __shared__ int cnt[256], off[256], gst[256];
    int tid = threadIdx.x;
    cnt[tid] = 0;
    __syncthreads();
    int base = blockIdx.x * 4096;
    bool i64 = (*flag) != 0;
    unsigned u[16];
    int bk[16];
#pragma unroll
    for (int k = 0; k < 16; ++k) {
        int e = base + tid + k * 256;
        if (e < E) {
            int s_, d_;
            if (i64) { s_ = ei[2 * (size_t)e]; d_ = ei[2 * ((size_t)E + e)]; }
            else     { s_ = ei[e];             d_ = ei[(size_t)E + e]; }
            bk[k] = d_ >> 8;
            u[k] = (unsigned)s_ | ((unsigned)(d_ & 255) << 16) | ((unsigned)bk[k] << 24);
            atomicAdd(&cnt[bk[k]], 1);
        } else bk[k] = -1;
    }
    __syncthreads();
    int c = cnt[tid];
    off[tid] = c;
    __syncthreads();
    for (int o = 1; o < 256; o <<= 1) {
        int v = (tid >= o) ? off[tid - o] : 0;
        __syncthreads();
        off[tid] += v;
        __syncthreads();
    }
    int incl = off[tid];
    __syncthreads();
    off[tid] = incl - c;   // exclusive start; advances to end via atomics
    __syncthreads();
#pragma unroll
    for (int k = 0; k < 16; ++k) {
        if (bk[k] >= 0) {
            int p = atomicAdd(&off[bk[k]], 1);
            sPair[p] = u[k];
        }
    }
    if (c > 0) gst[tid] = atomicAdd(&bucket_cursor[tid], c);
    __syncthreads();
    int total = off[255];
    for (int idx = tid; idx < total; idx += 256) {
        unsigned v = sPair[idx];
        int b = (int)(v >> 24);
        int bstart = off[b] - cnt[b];
        stage[gst[b] + (idx - bstart)] = v;
    }
}

// --- binned CSR phase B: one block per bucket, per-node cursors in LDS. ---
__global__ __launch_bounds__(256) void binB_kernel(
    const unsigned* __restrict__ stage, const int* __restrict__ rowptr,
    int Nn, int* __restrict__ col) {
    __shared__ int curs[256];
    int b = blockIdx.x, tid = threadIdx.x;
    int n0 = b << 8;
    if (n0 + tid < Nn) curs[tid] = rowptr[n0 + tid];
    __syncthreads();
    int s = rowptr[n0];
    int e = rowptr[min(n0 + 256, Nn)];
    for (int i = s + tid; i < e; i += 256) {
        unsigned u = stage[i];
        int p = atomicAdd(&curs[(u >> 16) & 255], 1);
        col[p] = (int)(u & 0xffffu);
    }
}

// x (fp32, N x 64) -> xb (bf16, N x 64)
__global__ void xconv_kernel(const float* __restrict__ x, ushort_t* __restrict__ xb, int total16) {
    int idx = blockIdx.x * blockDim.x + threadIdx.x;
    if (idx >= total16) return;
    float4 v = *(const float4*)&x[(size_t)idx * 4];
    ushort4 u;
    u.x = f2b(v.x); u.y = f2b(v.y); u.z = f2b(v.z); u.w = f2b(v.w);
    *(ushort4*)&xb[(size_t)idx * 4] = u;
}

// gout folding: Fl = gout_w @ wl_bot, Fr = gout_w @ wr_bot (fp32),
// bias2 = s0_b + gout_b @ wl_bot, cvec = gout_b @ wr_bot.
__global__ void foldw_kernel(const float* __restrict__ gw, const float* __restrict__ gb,
                             const float* __restrict__ s0wl, const float* __restrict__ s0wr,
                             const float* __restrict__ s0bias,
                             float* __restrict__ Fl, float* __restrict__ Fr,
                             float* __restrict__ bias2, float* __restrict__ cvec) {
    int idx = blockIdx.x * blockDim.x + threadIdx.x;   // 128*256
    if (idx >= 128 * 256) return;
    int k = idx >> 8, n = idx & 255;
    const float* wl = s0wl + 64 * 256;   // rows 64..191
    const float* wr = s0wr + 64 * 256;
    float al = 0.f, ar = 0.f;
    for (int j = 0; j < 128; ++j) {
        float g = gw[k * 128 + j];
        al += g * wl[j * 256 + n];
        ar += g * wr[j * 256 + n];
    }
    Fl[k * 256 + n] = al;
    Fr[k * 256 + n] = ar;
    if (k == 0) {
        float bl = 0.f, br = 0.f;
        for (int j = 0; j < 128; ++j) {
            float g = gb[j];
            bl += g * wl[j * 256 + n];
            br += g * wr[j * 256 + n];
        }
        bias2[n] = s0bias[n] + bl;
        cvec[n] = br;
    }
}

// ---------------------------------------------------------------------------
// Weight convert + pack into MFMA fragment order.
// off = ((n>>4)*(K>>5) + (k>>5))*512 + ((n&15)|(((k>>3)&3)<<4))*8 + (k&7)
// ---------------------------------------------------------------------------
struct WtDesc { const float* src; ushort_t* dst; int lk2; int K; int N; int base; };
struct WtArgs { WtDesc d[10]; int total; };
__global__ void wtconv_kernel(WtArgs a) {
    int idx = blockIdx.x * blockDim.x + threadIdx.x;
    if (idx >= a.total) return;
    int s = 0;
#pragma unroll
    for (int i = 1; i < 10; ++i) if (idx >= a.d[i].base) s = i;
    int local = idx - a.d[s].base;
    int K = a.d[s].K;
    int n = local >> a.d[s].lk2;
    int k = local & (K - 1);
    unsigned off = (unsigned)((n >> 4) * (K >> 5) + (k >> 5)) * 512u
                 + (unsigned)(((n & 15) | (((k >> 3) & 3) << 4)) << 3) + (unsigned)(k & 7);
    a.d[s].dst[off] = f2b(a.d[s].src[(size_t)k * a.d[s].N + n]);
}

// ---------------------------------------------------------------------------
// bf16 gather aggregation: one wave per node, lane handles VEC bf16.
// MODE 0: out[i] = h[i] + sum_nbr h[j]   MODE 1: out[i] = invdeg[i]*sum h[j]
// Wave-uniform rowptr bounds via readfirstlane -> scalar col loads.
// ---------------------------------------------------------------------------
template <int VEC>
__device__ __forceinline__ void ldrow(const ushort_t* p, float* t) {
    if constexpr (VEC == 1) {
        t[0] = b2f(p[0]);
    } else if constexpr (VEC == 2) {
        unsigned int v = *(const unsigned int*)p;
        t[0] = b2f(v & 0xffffu); t[1] = b2f(v >> 16);
    } else {
        uint2 v = *(const uint2*)p;
        t[0] = b2f(v.x & 0xffffu); t[1] = b2f(v.x >> 16);
        t[2] = b2f(v.y & 0xffffu); t[3] = b2f(v.y >> 16);
    }
}

template <int VEC, int MODE>
__global__ __launch_bounds__(256) void aggb_kernel(
    const ushort_t* __restrict__ h, int ldh,
    const int* __restrict__ rowptr, const int* __restrict__ col,
    const float* __restrict__ invdeg,
    ushort_t* __restrict__ out, int ldo, int Nn, int lanes) {
    int wid = blockIdx.x * 4 + ((int)threadIdx.x >> 6);
    int lane = (int)threadIdx.x & 63;
    if (wid >= Nn || lane >= lanes) return;

    const ushort_t* hb = h + (size_t)lane * VEC;
    float a[VEC], b2a[VEC];
#pragma unroll
    for (int v = 0; v < VEC; ++v) { a[v] = 0.f; b2a[v] = 0.f; }

    int p0 = __builtin_amdgcn_readfirstlane(rowptr[wid]);
    int p1 = __builtin_amdgcn_readfirstlane(rowptr[wid + 1]);
    int p = p0;
    for (; p + 8 <= p1; p += 8) {
        int j0 = col[p], j1 = col[p + 1], j2 = col[p + 2], j3 = col[p + 3];
        int j4 = col[p + 4], j5 = col[p + 5], j6 = col[p + 6], j7 = col[p + 7];
        float t0[VEC], t1[VEC], t2[VEC], t3[VEC], t4[VEC], t5[VEC], t6[VEC], t7[VEC];
        ldrow<VEC>(hb + (size_t)j0 * ldh, t0);
        ldrow<VEC>(hb + (size_t)j1 * ldh, t1);
        ldrow<VEC>(hb + (size_t)j2 * ldh, t2);
        ldrow<VEC>(hb + (size_t)j3 * ldh, t3);
        ldrow<VEC>(hb + (size_t)j4 * ldh, t4);
        ldrow<VEC>(hb + (size_t)j5 * ldh, t5);
        ldrow<VEC>(hb + (size_t)j6 * ldh, t6);
        ldrow<VEC>(hb + (size_t)j7 * ldh, t7);
#pragma unroll
        for (int v = 0; v < VEC; ++v) {
            a[v]  += (t0[v] + t1[v]) + (t2[v] + t3[v]);
            b2a[v] += (t4[v] + t5[v]) + (t6[v] + t7[v]);
        }
    }
    for (; p + 4 <= p1; p += 4) {
        int j0 = col[p], j1 = col[p + 1], j2 = col[p + 2], j3 = col[p + 3];
        float t0[VEC], t1[VEC], t2[VEC], t3[VEC];
        ldrow<VEC>(hb + (size_t)j0 * ldh, t0);
        ldrow<VEC>(hb + (size_t)j1 * ldh, t1);
        ldrow<VEC>(hb + (size_t)j2 * ldh, t2);
        ldrow<VEC>(hb + (size_t)j3 * ldh, t3);
#pragma unroll
        for (int v = 0; v < VEC; ++v) a[v] += (t0[v] + t1[v]) + (t2[v] + t3[v]);
    }
    for (; p < p1; ++p) {
        float t[VEC];
        ldrow<VEC>(hb + (size_t)col[p] * ldh, t);
#pragma unroll
        for (int v = 0; v < VEC; ++v) a[v] += t[v];
    }
#pragma unroll
    for (int v = 0; v < VEC; ++v) a[v] += b2a[v];

    if constexpr (MODE == 0) {
        float t[VEC];
        ldrow<VEC>(hb + (size_t)wid * ldh, t);
#pragma unroll
        for (int v = 0; v < VEC; ++v) a[v] += t[v];
    } else {
        float s = invdeg[wid];
#pragma unroll
        for (int v = 0; v < VEC; ++v) a[v] *= s;
    }

    ushort_t* op = out + (size_t)wid * ldo + (size_t)lane * VEC;
    if constexpr (VEC == 1) {
        op[0] = f2b(a[0]);
    } else if constexpr (VEC == 2) {
        unsigned int v = (unsigned int)f2b(a[0]) | ((unsigned int)f2b(a[1]) << 16);
        *(unsigned int*)op = v;
    } else {
        uint2 v;
        v.x = (unsigned int)f2b(a[0]) | ((unsigned int)f2b(a[1]) << 16);
        v.y = (unsigned int)f2b(a[2]) | ((unsigned int)f2b(a[3]) << 16);
        *(uint2*)op = v;
    }
}

// Merged x-gather: out32 = GIN-0 input (32-wide), out64 = mean1-x (64-wide)
__global__ __launch_bounds__(256) void aggdual_kernel(
    const ushort_t* __restrict__ xb,
    const int* __restrict__ rowptr, const int* __restrict__ col,
    const float* __restrict__ invdeg,
    ushort_t* __restrict__ out32, ushort_t* __restrict__ out64, int Nn) {
    int wid = blockIdx.x * 4 + ((int)threadIdx.x >> 6);
    int lane = (int)threadIdx.x & 63;
    if (wid >= Nn) return;
    const ushort_t* hb = xb + lane;
    float a = 0.f, b2a = 0.f;
    int p0 = __builtin_amdgcn_readfirstlane(rowptr[wid]);
    int p1 = __builtin_amdgcn_readfirstlane(rowptr[wid + 1]);
    int p = p0;
    for (; p + 8 <= p1; p += 8) {
        float v0 = b2f(hb[(size_t)col[p] * 64]);
        float v1 = b2f(hb[(size_t)col[p + 1] * 64]);
        float v2 = b2f(hb[(size_t)col[p + 2] * 64]);
        float v3 = b2f(hb[(size_t)col[p + 3] * 64]);
        float v4 = b2f(hb[(size_t)col[p + 4] * 64]);
        float v5 = b2f(hb[(size_t)col[p + 5] * 64]);
        float v6 = b2f(hb[(size_t)col[p + 6] * 64]);
        float v7 = b2f(hb[(size_t)col[p + 7] * 64]);
        a += (v0 + v1) + (v2 + v3);
        b2a += (v4 + v5) + (v6 + v7);
    }
    for (; p + 4 <= p1; p += 4) {
        float v0 = b2f(hb[(size_t)col[p] * 64]);
        float v1 = b2f(hb[(size_t)col[p + 1] * 64]);
        float v2 = b2f(hb[(size_t)col[p + 2] * 64]);
        float v3 = b2f(hb[(size_t)col[p + 3] * 64]);
        a += (v0 + v1) + (v2 + v3);
    }
    for (; p < p1; ++p) a += b2f(hb[(size_t)col[p] * 64]);
    a += b2a;
    out64[(size_t)wid * 64 + lane] = f2b(a * invdeg[wid]);
    if (lane < 32) {
        float self = b2f(hb[(size_t)wid * 64]);
        out32[(size_t)wid * 32 + lane] = f2b(a + self);
    }
}

// ---------------------------------------------------------------------------
// Chain-fused bf16 MFMA GEMM, R15 schedule (async global->LDS staging) +
// optional in-register projection epilogue (pzl != nullptr): each row of the
// result is projected onto pwl/pwr (256->2 each) via shfl_xor reduce over the
// 16 lr-lanes and fp32 atomicAdd into pzl/pz (eliminates the s0b buffer).
// ---------------------------------------------------------------------------
struct GPass { const ushort_t* A; const ushort_t* Wp; int lda; int K; };
struct FArgs {
    GPass p[4]; int np;
    const ushort_t* W2p;                         // chain==2 second GEMM W
    const float* b1; const float* b2;
    int relu1, relu2;
    int chain;                                   // 1..2
    const float* rowmask; const float* cvec;     // optional rank-1 term
    const float* pwl; const float* pwr;          // projection weights [256][2]
    float* pzl; float* pz;                       // projection outputs (2N fp32 each)
};

__global__ __launch_bounds__(512) void fgemm_kernel(
    FArgs fa, int M, ushort_t* __restrict__ out, int ldc) {
    __shared__ __align__(16) ushort_t Tlds[8192];          // 16 KB
    __shared__ __align__(16) ushort_t Wlds[16384];         // 32 KB

    int rowbase = blockIdx.x * 64;
    int colbase = blockIdx.y * 128;
    int tid = threadIdx.x;
    int lane = tid & 63, w = tid >> 6;           // 8 waves
    int wr3 = w & 3, wc2 = w >> 2;
    int lr = lane & 15, rq = (lane >> 4) * 4;

    f32x4 acc[4];
#pragma unroll
    for (int j = 0; j < 4; ++j) acc[j] = (f32x4){0.f, 0.f, 0.f, 0.f};

    u32x4 w2a = (u32x4){0u,0u,0u,0u}, w2b = w2a, w2c = w2a, w2d = w2a;

    for (int q = 0; q < fa.np; ++q) {
        const ushort_t* A = fa.p[q].A;
        const ushort_t* Wp = fa.p[q].Wp;
        int lda = fa.p[q].lda, K = fa.p[q].K;
        int nch = K >> 5;

        // async stage W slab: nch*512 uint4s, lane-contiguous
        {
            const ushort_t* wsrc = &Wp[((size_t)(colbase >> 4) * nch) * 512];
            for (int j = 0; j < nch; ++j) {
                int i = w * 64 + j * 512;        // wave-uniform uint4 base
                gload_lds16(wsrc + (size_t)(i + lane) * 8, &Wlds[i * 8]);
            }
        }
        // async stage A tile: subtile (c, rgrp) per wave-iteration, 16B/lane
        for (int s = w; s < nch * 4; s += 8) {
            int c = s >> 2, rgrp = s & 3;
            int gr = rowbase + rgrp * 16 + lr;
            int gcol = c * 32 + (lane >> 4) * 8;
            if (gr < M)
                gload_lds16(&A[(size_t)gr * lda + gcol], &Tlds[c * 2048 + rgrp * 512]);
        }
        // prefetch chain W2 into static registers (latency hides under GEMM1)
        if (q == 0 && fa.chain >= 2) {
            const u32x4* w2src = (const u32x4*)fa.W2p;
            w2a = w2src[tid];
            w2b = w2src[tid + 512];
            w2c = w2src[tid + 1024];
            w2d = w2src[tid + 1536];
        }
        __syncthreads();
        int cgl0 = wc2 * 4;
        for (int c = 0; c < nch; ++c) {
            bf16x8 af = *(const bf16x8*)&Tlds[c * 2048 + wr3 * 512 + lane * 8];
            bf16x8 bfr[4];
#pragma unroll
            for (int j = 0; j < 4; ++j)
                bfr[j] = *(const bf16x8*)&Wlds[(((cgl0 + j) * nch) + c) * 512 + lane * 8];
#pragma unroll
            for (int j = 0; j < 4; ++j)
                acc[j] = __builtin_amdgcn_mfma_f32_16x16x32_bf16(af, bfr[j], acc[j], 0, 0, 0);
        }
        __syncthreads();
    }

    if (fa.chain >= 2) {
        // W2 from registers -> LDS (no global latency here)
        ((u32x4*)Wlds)[tid] = w2a;
        ((u32x4*)Wlds)[tid + 512] = w2b;
        ((u32x4*)Wlds)[tid + 1024] = w2c;
        ((u32x4*)Wlds)[tid + 1536] = w2d;
        // epilogue of GEMM1 -> Tlds in fragment layout (A2[row][k=colj])
#pragma unroll
        for (int j = 0; j < 4; ++j) {
            int colj = wc2 * 64 + j * 16 + lr;
            float bv = fa.b1[colj];
            int kk = colj & 31;
            int cof = (colj >> 5) * 2048 + ((((kk >> 3) << 4)) << 3) + (kk & 7);
#pragma unroll
            for (int t = 0; t < 4; ++t) {
                int row = wr3 * 16 + rq + t;
                float v = acc[j][t] + bv;
                if (fa.relu1) v = fmaxf(v, 0.f);
                Tlds[cof + wr3 * 512 + ((row & 15) << 3)] = f2b(v);
            }
            acc[j] = (f32x4){0.f, 0.f, 0.f, 0.f};
        }
        __syncthreads();
        int cgl0 = wc2 * 4;
        for (int c = 0; c < 4; ++c) {
            bf16x8 af = *(const bf16x8*)&Tlds[c * 2048 + wr3 * 512 + lane * 8];
            bf16x8 bfr[4];
#pragma unroll
            for (int j = 0; j < 4; ++j)
                bfr[j] = *(const bf16x8*)&Wlds[((cgl0 + j) * 4 + c) * 512 + lane * 8];
#pragma unroll
            for (int j = 0; j < 4; ++j)
                acc[j] = __builtin_amdgcn_mfma_f32_16x16x32_bf16(af, bfr[j], acc[j], 0, 0, 0);
        }
        __syncthreads();
    }

    const float* bf_ = (fa.chain == 1) ? fa.b1 : fa.b2;
    int reluf = (fa.chain == 1) ? fa.relu1 : fa.relu2;
    float rm[4];
#pragma unroll
    for (int t = 0; t < 4; ++t) {
        int gr = rowbase + wr3 * 16 + rq + t;
        rm[t] = (fa.cvec && gr < M) ? fa.rowmask[gr] : 0.f;
    }

    if (fa.pzl) {
        // ---- projection epilogue: per-row dots onto pwl/pwr ----
        float part[4][4];
#pragma unroll
        for (int t = 0; t < 4; ++t)
#pragma unroll
            for (int k = 0; k < 4; ++k) part[t][k] = 0.f;
#pragma unroll
        for (int j = 0; j < 4; ++j) {
            int c = colbase + wc2 * 64 + j * 16 + lr;
            float bv = bf_[c];
            float cv = fa.cvec ? fa.cvec[c] : 0.f;
            float wl0 = fa.pwl[2 * c], wl1 = fa.pwl[2 * c + 1];
            float wr0 = fa.pwr[2 * c], wr1 = fa.pwr[2 * c + 1];
#pragma unroll
            for (int t = 0; t < 4; ++t) {
                float v = acc[j][t] + bv + rm[t] * cv;
                if (reluf) v = fmaxf(v, 0.f);
                part[t][0] += v * wl0;
                part[t][1] += v * wl1;
                part[t][2] += v * wr0;
                part[t][3] += v * wr1;
            }
        }
        // reduce over the 16 lr-lanes (same rows within each hi group)
#pragma unroll
        for (int t = 0; t < 4; ++t)
#pragma unroll
            for (int k = 0; k < 4; ++k) {
                float s = part[t][k];
                s += __shfl_xor(s, 1);
                s += __shfl_xor(s, 2);
                s += __shfl_xor(s, 4);
                s += __shfl_xor(s, 8);
                part[t][k] = s;
            }
        if (lr == 0) {
#pragma unroll
            for (int t = 0; t < 4; ++t) {
                int gr = rowbase + wr3 * 16 + rq + t;
                if (gr < M) {
                    atomicAdd(&fa.pzl[2 * gr], part[t][0]);
                    atomicAdd(&fa.pzl[2 * gr + 1], part[t][1]);
                    atomicAdd(&fa.pz[2 * gr], part[t][2]);
                    atomicAdd(&fa.pz[2 * gr + 1], part[t][3]);
                }
            }
        }
        return;
    }

    // ---- standard epilogue: linear LDS stage -> coalesced bf16 store ----
#pragma unroll
    for (int j = 0; j < 4; ++j) {
        int colj = wc2 * 64 + j * 16 + lr;
        float bv = bf_[colbase + colj];
        float cv = fa.cvec ? fa.cvec[colbase + colj] : 0.f;
#pragma unroll
        for (int t = 0; t < 4; ++t) {
            int row = wr3 * 16 + rq + t;
            float v = acc[j][t] + bv + rm[t] * cv;
            if (reluf) v = fmaxf(v, 0.f);
            Tlds[row * 128 + colj] = f2b(v);
        }
    }
    __syncthreads();
    for (int u = tid; u < 1024; u += 512) {
        int row = u >> 4, seg = u & 15;
        int gr = rowbase + row;
        if (gr < M)
            *(u32x4*)&out[(size_t)gr * ldc + colbase + seg * 8] =
                *(const u32x4*)&Tlds[row * 128 + seg * 8];
    }
}

// out[i] = zl[i] + invdeg[i] * sum_nbr z[j] + b ; one thread per node
__global__ void aggz_kernel(const float2* __restrict__ z, const float2* __restrict__ zl,
                            const int* __restrict__ rowptr, const int* __restrict__ col,
                            const float* __restrict__ invdeg, const float* __restrict__ b,
                            float* __restrict__ out, int Nn) {
    int i = blockIdx.x * blockDim.x + threadIdx.x;
    if (i >= Nn) return;
    float s0 = 0.f, s1 = 0.f;
    int p = rowptr[i], p1 = rowptr[i + 1];
    for (; p + 4 <= p1; p += 4) {
        float2 a = z[col[p]], c = z[col[p + 1]], d = z[col[p + 2]], e = z[col[p + 3]];
        s0 += (a.x + c.x) + (d.x + e.x);
        s1 += (a.y + c.y) + (d.y + e.y);
    }
    for (; p < p1; ++p) {
        float2 a = z[col[p]];
        s0 += a.x; s1 += a.y;
    }
    float inv = invdeg[i];
    float2 l = zl[i];
    out[(size_t)i * 2 + 0] = l.x + inv * s0 + b[0];
    out[(size_t)i * 2 + 1] = l.y + inv * s1 + b[1];
}

extern "C" void kernel_launch(void* const* d_in, const int* in_sizes, int n_in,
                              void* d_out, int out_size, void* d_ws, size_t ws_size,
                              hipStream_t stream) {
    const float* x      = (const float*)d_in[0];
    const int*   ei     = (const int*)d_in[1];
    const float* g_w1[3] = {(const float*)d_in[2], (const float*)d_in[6],  (const float*)d_in[10]};
    const float* g_b1[3] = {(const float*)d_in[3], (const float*)d_in[7],  (const float*)d_in[11]};
    const float* g_w2[3] = {(const float*)d_in[4], (const float*)d_in[8],  (const float*)d_in[12]};
    const float* g_b2[3] = {(const float*)d_in[5], (const float*)d_in[9],  (const float*)d_in[13]};
    const float* gout_w = (const float*)d_in[14];
    const float* gout_b = (const float*)d_in[15];
    const float* s0_wl  = (const float*)d_in[16];
    const float* s0_wr  = (const float*)d_in[17];
    const float* s0_b   = (const float*)d_in[18];
    const float* s1_wl  = (const float*)d_in[19];
    const float* s1_wr  = (const float*)d_in[20];
    const float* s1_b   = (const float*)d_in[21];
    float* out = (float*)d_out;

    const int N = in_sizes[0] / 64;
    const int E = in_sizes[1] / 2;

    char* ws = (char*)d_ws;
    size_t o = 0;
    auto take = [&](size_t bytes) -> char* {
        char* p = ws + o;
        o = (o + bytes + 255) & ~(size_t)255;
        return p;
    };
    ushort_t* xb     = (ushort_t*)take((size_t)N * 64 * 2);
    ushort_t* bA     = (ushort_t*)take((size_t)N * 128 * 2);
    ushort_t* bB     = (ushort_t*)take((size_t)N * 128 * 2);
    ushort_t* bC     = (ushort_t*)take((size_t)N * 128 * 2);
    ushort_t* aggxb  = (ushort_t*)take((size_t)N * 64 * 2);
    ushort_t* agggb  = (ushort_t*)take((size_t)N * 128 * 2);
    float2*   zlb    = (float2*)take((size_t)N * 2 * 4);
    float2*   zb     = (float2*)take((size_t)N * 2 * 4);
    float* Flbuf = (float*)take(128 * 256 * 4);
    float* Frbuf = (float*)take(128 * 256 * 4);
    float* bias2 = (float*)take(256 * 4);
    float* cvecb = (float*)take(256 * 4);
    ushort_t* w1t0 = (ushort_t*)take(128 * 32 * 2);
    ushort_t* w2t0 = (ushort_t*)take(128 * 128 * 2);
    ushort_t* w1t1 = (ushort_t*)take(128 * 128 * 2);
    ushort_t* w2t1 = (ushort_t*)take(128 * 128 * 2);
    ushort_t* w1t2 = (ushort_t*)take(128 * 128 * 2);
    ushort_t* w2t2 = (ushort_t*)take(128 * 128 * 2);
    ushort_t* wltop = (ushort_t*)take(256 * 64 * 2);
    ushort_t* wglp  = (ushort_t*)take(256 * 128 * 2);
    ushort_t* wrtop = (ushort_t*)take(256 * 64 * 2);
    ushort_t* wgrp  = (ushort_t*)take(256 * 128 * 2);
    unsigned* stage  = (unsigned*)take((size_t)E * 4);
    int*   colI   = (int*)take((size_t)E * 4);
    int*   rowptr = (int*)take((size_t)(N + 1) * 4);
    int*   deg    = (int*)take((size_t)N * 4);
    float* invdeg = (float*)take((size_t)N * 4);
    float* maskb  = (float*)take((size_t)N * 4);
    int*   blocksum = (int*)take(256 * 4);
    int*   blockoff = (int*)take(256 * 4);
    int*   bucket_cursor = (int*)take(512 * 4);
    int*   flag   = (int*)take(4);

    hipMemsetAsync(deg, 0, (size_t)N * 4, stream);
    hipMemsetAsync(flag, 1, 4, stream);
    hipMemsetAsync(zlb, 0, (size_t)N * 2 * 4, stream);
    hipMemsetAsync(zb, 0, (size_t)N * 2 * 4, stream);

    const int TB = 256;
    const int nb = (N + 2047) / 2048;
    const int NBKT = (N + 255) >> 8;

    // --- CSR by dst: deg -> scan -> binned two-phase build ---
    detect_kernel<<<4, TB, 0, stream>>>(ei, 1024, flag);
    deg_kernel<<<(E + TB - 1) / TB, TB, 0, stream>>>(ei, E, flag, deg);
    scanA_kernel<<<nb, 256, 0, stream>>>(deg, N, rowptr, blocksum);
    scanB_kernel<<<1, 256, 0, stream>>>(blocksum, nb, blockoff, rowptr, N);
    scanC_kernel<<<(N + TB - 1) / TB, TB, 0, stream>>>(deg, N, blockoff, rowptr, invdeg, maskb, bucket_cursor);
    binA_kernel<<<(E + 4095) / 4096, 256, 0, stream>>>(ei, E, flag, bucket_cursor, stage);
    binB_kernel<<<NBKT, 256, 0, stream>>>(stage, rowptr, N, colI);

    // --- gout fold (fp32) + weight convert/pack ---
    foldw_kernel<<<128, 256, 0, stream>>>(gout_w, gout_b, s0_wl, s0_wr, s0_b,
                                          Flbuf, Frbuf, bias2, cvecb);
    WtArgs wa;
    const float* wsrc[10] = {g_w1[0], g_w2[0], g_w1[1], g_w2[1], g_w1[2], g_w2[2],
                             s0_wl, Flbuf, s0_wr, Frbuf};
    ushort_t* wdst[10]    = {w1t0, w2t0, w1t1, w2t1, w1t2, w2t2,
                             wltop, wglp, wrtop, wgrp};
    int wk[10]  = {32, 128, 128, 128, 128, 128, 64, 128, 64, 128};
    int wl2[10] = {5, 7, 7, 7, 7, 7, 6, 7, 6, 7};
    int wn[10]  = {128, 128, 128, 128, 128, 128, 256, 256, 256, 256};
    int base = 0;
    for (int i = 0; i < 10; ++i) {
        wa.d[i].src = wsrc[i]; wa.d[i].dst = wdst[i];
        wa.d[i].lk2 = wl2[i]; wa.d[i].K = wk[i]; wa.d[i].N = wn[i]; wa.d[i].base = base;
        base += wk[i] * wn[i];
    }
    wa.total = base;
    wtconv_kernel<<<(base + TB - 1) / TB, TB, 0, stream>>>(wa);

    // --- x -> bf16 ---
    xconv_kernel<<<((N * 16) + TB - 1) / TB, TB, 0, stream>>>(x, xb, N * 16);

    const int AGG_GRID = (N + 3) / 4;
    const int GX = (N + 63) / 64;

    // merged x-gather: bB = GIN-0 input (32-wide), aggxb = mean1-x (64-wide)
    aggdual_kernel<<<AGG_GRID, 256, 0, stream>>>(xb, rowptr, colI, invdeg, bB, aggxb, N);

    // --- GIN layer 0 (chain=2): bB -> h1 = bA ---
    {
        FArgs fa = {};
        fa.p[0] = {bB, w1t0, 32, 32};
        fa.np = 1;
        fa.W2p = w2t0;
        fa.b1 = g_b1[0]; fa.b2 = g_b2[0];
        fa.relu1 = 1; fa.relu2 = 1;
        fa.chain = 2;
        fgemm_kernel<<<dim3(GX, 1), 512, 0, stream>>>(fa, N, bA, 128);
    }

    // --- GIN layer 1: bA -> agg bB -> h2 = bC ---
    aggb_kernel<2, 0><<<AGG_GRID, 256, 0, stream>>>(bA, 128, rowptr, colI, invdeg, bB, 128, N, 64);
    {
        FArgs fa = {};
        fa.p[0] = {bB, w1t1, 128, 128};
        fa.np = 1;
        fa.W2p = w2t1;
        fa.b1 = g_b1[1]; fa.b2 = g_b2[1];
        fa.relu1 = 1; fa.relu2 = 1;
        fa.chain = 2;
        fgemm_kernel<<<dim3(GX, 1), 512, 0, stream>>>(fa, N, bC, 128);
    }

    // --- GIN layer 2 (chain=2): bC -> agg bB -> h3 = bA ---
    aggb_kernel<2, 0><<<AGG_GRID, 256, 0, stream>>>(bC, 128, rowptr, colI, invdeg, bB, 128, N, 64);
    {
        FArgs fa = {};
        fa.p[0] = {bB, w1t2, 128, 128};
        fa.np = 1;
        fa.W2p = w2t2;
        fa.b1 = g_b1[2]; fa.b2 = g_b2[2];
        fa.relu1 = 1; fa.relu2 = 1;
        fa.chain = 2;
        fgemm_kernel<<<dim3(GX, 1), 512, 0, stream>>>(fa, N, bA, 128);
    }

    // mean-agg(h3) (gout folded into s0 weights)
    aggb_kernel<2, 1><<<AGG_GRID, 256, 0, stream>>>(bA, 128, rowptr, colI, invdeg, agggb, 128, N, 64);

    // s0 = relu(x@wltop + h3@Fl + aggx@wrtop + aggh3@Fr + bias2 + mask.cvec),
    // fused with projection onto s1_wl/s1_wr (writes zl, z; never materializes s0)
    {
        FArgs fa = {};
        fa.p[0] = {xb, wltop, 64, 64};
        fa.p[1] = {bA, wglp, 128, 128};
        fa.p[2] = {aggxb, wrtop, 64, 64};
        fa.p[3] = {agggb, wgrp, 128, 128};
        fa.np = 4;
        fa.b1 = bias2;
        fa.relu1 = 1;
        fa.chain = 1;
        fa.rowmask = maskb; fa.cvec = cvecb;
        fa.pwl = s1_wl; fa.pwr = s1_wr;
        fa.pzl = (float*)zlb; fa.pz = (float*)zb;
        fgemm_kernel<<<dim3(GX, 2), 512, 0, stream>>>(fa, N, nullptr, 0);
    }

    // out = zl + invdeg * agg(z) + b
    aggz_kernel<<<(N + TB - 1) / TB, TB, 0, stream>>>(zb, zlb, rowptr, colI, invdeg, s1_b, out, N);
}

// Round 19
// 320.010 us; speedup vs baseline: 1.0221x; 1.0221x over previous
//
#include <hip/hip_runtime.h>

// ---------------------------------------------------------------------------
// GAMLNET GNN forward, bf16 edition, R18.
// R18 = R17 with the projection-fused s0 GEMM split into its OWN kernel:
// R17 put the projection branch inside the shared fgemm kernel, raising VGPR
// 40->44 and slowing the three chain GEMMs 43.5->55.6us (codegen
// perturbation). fgemm_kernel is now byte-identical to R16; fgemm_proj_kernel
// carries only the np=4 + projection path.
// NOTE: edge packing assumes N <= 65536 (problem fixes N=50000).
// ---------------------------------------------------------------------------

typedef unsigned short ushort_t;
typedef __bf16 bf16x8 __attribute__((ext_vector_type(8)));
typedef float f32x4 __attribute__((ext_vector_type(4)));
typedef unsigned u32x4 __attribute__((ext_vector_type(4)));

__device__ __forceinline__ float b2f(unsigned int u16) {
    union { unsigned int i; float f; } v;
    v.i = u16 << 16;
    return v.f;
}
__device__ __forceinline__ unsigned short f2b(float f) {
    union { float f; unsigned int i; } v;
    v.f = f;
    unsigned int x = v.i;
    unsigned int r = (x + 0x7fffu + ((x >> 16) & 1u)) >> 16;  // RNE
    return (unsigned short)r;
}

// async 16-byte global -> LDS copy (lane-level; LDS dest = uniform base + lane*16)
__device__ __forceinline__ void gload_lds16(const void* g, void* l) {
    __builtin_amdgcn_global_load_lds(
        (const __attribute__((address_space(1))) unsigned int*)g,
        (__attribute__((address_space(3))) unsigned int*)l,
        16, 0, 0);
}

// --- edge dtype detection: if input is int64, odd int32 words are all zero ---
__global__ void detect_kernel(const int* __restrict__ ei, int ncheck, int* flag) {
    int t = blockIdx.x * blockDim.x + threadIdx.x;
    if (t < ncheck) {
        if (ei[2 * t + 1] != 0) atomicAnd(flag, 0);
    }
}

// deg count straight from edge_index (flag-branched layout)
__global__ void deg_kernel(const int* __restrict__ ei, int E, const int* __restrict__ flag,
                           int* __restrict__ deg) {
    int e = blockIdx.x * blockDim.x + threadIdx.x;
    if (e >= E) return;
    int d = (*flag) ? ei[2 * ((size_t)E + e)] : ei[(size_t)E + e];
    atomicAdd(&deg[d], 1);
}

// --- 3-phase multi-block exclusive scan (2048 elements per block) ---
__global__ __launch_bounds__(256) void scanA_kernel(const int* __restrict__ deg, int n,
                                                    int* __restrict__ rowptr,
                                                    int* __restrict__ blocksum) {
    __shared__ int sh[256];
    int b = blockIdx.x, tid = threadIdx.x;
    int base = b * 2048 + tid * 8;
    int v[8];
#pragma unroll
    for (int e = 0; e < 8; ++e) {
        int i = base + e;
        v[e] = (i < n) ? deg[i] : 0;
    }
    int t = 0;
#pragma unroll
    for (int e = 0; e < 8; ++e) { int x = v[e]; v[e] = t; t += x; }
    sh[tid] = t;
    __syncthreads();
    for (int off = 1; off < 256; off <<= 1) {
        int val = (tid >= off) ? sh[tid - off] : 0;
        __syncthreads();
        sh[tid] += val;
        __syncthreads();
    }
    int excl = sh[tid] - t;
#pragma unroll
    for (int e = 0; e < 8; ++e) {
        int i = base + e;
        if (i < n) rowptr[i] = excl + v[e];
    }
    if (tid == 255) blocksum[b] = sh[255];
}

__global__ __launch_bounds__(256) void scanB_kernel(const int* __restrict__ blocksum, int nb,
                                                    int* __restrict__ blockoff,
                                                    int* __restrict__ rowptr, int n) {
    __shared__ int sh[256];
    int tid = threadIdx.x;
    int v = (tid < nb) ? blocksum[tid] : 0;
    sh[tid] = v;
    __syncthreads();
    for (int off = 1; off < 256; off <<= 1) {
        int t = (tid >= off) ? sh[tid - off] : 0;
        __syncthreads();
        sh[tid] += t;
        __syncthreads();
    }
    if (tid < nb) blockoff[tid] = sh[tid] - v;
    if (tid == 255) rowptr[n] = sh[255];
}

// finalize rowptr, compute invdeg/mask, and init per-bucket cursors
__global__ void scanC_kernel(const int* __restrict__ deg, int n, const int* __restrict__ blockoff,
                             int* __restrict__ rowptr, float* __restrict__ invdeg,
                             float* __restrict__ mask, int* __restrict__ bucket_cursor) {
    int i = blockIdx.x * blockDim.x + threadIdx.x;
    if (i >= n) return;
    int r = rowptr[i] + blockoff[i >> 11];
    rowptr[i] = r;
    if ((i & 255) == 0) bucket_cursor[i >> 8] = r;
    int d = deg[i];
    invdeg[i] = 1.0f / fmaxf((float)d, 1.0f);
    mask[i] = (d > 0) ? 1.0f : 0.0f;
}

// --- binned CSR phase A: LDS counting-sort of 4096-edge chunks by dst>>8,
//     parallel flush (bucket id packed in bits 24-31). ---
__global__ __launch_bounds__(256) void binA_kernel(
    const int* __restrict__ ei, int E, const int* __restrict__ flag,
    int* __restrict__ bucket_cursor, unsigned* __restrict__ stage) {
    __shared__ unsigned sPair[4096];      // 16 KB
    __shared__ int cnt[256], off[256], gst[256];
    int tid = threadIdx.x;
    cnt[tid] = 0;
    __syncthreads();
    int base = blockIdx.x * 4096;
    bool i64 = (*flag) != 0;
    unsigned u[16];
    int bk[16];
#pragma unroll
    for (int k = 0; k < 16; ++k) {
        int e = base + tid + k * 256;
        if (e < E) {
            int s_, d_;
            if (i64) { s_ = ei[2 * (size_t)e]; d_ = ei[2 * ((size_t)E + e)]; }
            else     { s_ = ei[e];             d_ = ei[(size_t)E + e]; }
            bk[k] = d_ >> 8;
            u[k] = (unsigned)s_ | ((unsigned)(d_ & 255) << 16) | ((unsigned)bk[k] << 24);
            atomicAdd(&cnt[bk[k]], 1);
        } else bk[k] = -1;
    }
    __syncthreads();
    int c = cnt[tid];
    off[tid] = c;
    __syncthreads();
    for (int o = 1; o < 256; o <<= 1) {
        int v = (tid >= o) ? off[tid - o] : 0;
        __syncthreads();
        off[tid] += v;
        __syncthreads();
    }
    int incl = off[tid];
    __syncthreads();
    off[tid] = incl - c;   // exclusive start; advances to end via atomics
    __syncthreads();
#pragma unroll
    for (int k = 0; k < 16; ++k) {
        if (bk[k] >= 0) {
            int p = atomicAdd(&off[bk[k]], 1);
            sPair[p] = u[k];
        }
    }
    if (c > 0) gst[tid] = atomicAdd(&bucket_cursor[tid], c);
    __syncthreads();
    int total = off[255];
    for (int idx = tid; idx < total; idx += 256) {
        unsigned v = sPair[idx];
        int b = (int)(v >> 24);
        int bstart = off[b] - cnt[b];
        stage[gst[b] + (idx - bstart)] = v;
    }
}

// --- binned CSR phase B: one block per bucket, per-node cursors in LDS. ---
__global__ __launch_bounds__(256) void binB_kernel(
    const unsigned* __restrict__ stage, const int* __restrict__ rowptr,
    int Nn, int* __restrict__ col) {
    __shared__ int curs[256];
    int b = blockIdx.x, tid = threadIdx.x;
    int n0 = b << 8;
    if (n0 + tid < Nn) curs[tid] = rowptr[n0 + tid];
    __syncthreads();
    int s = rowptr[n0];
    int e = rowptr[min(n0 + 256, Nn)];
    for (int i = s + tid; i < e; i += 256) {
        unsigned u = stage[i];
        int p = atomicAdd(&curs[(u >> 16) & 255], 1);
        col[p] = (int)(u & 0xffffu);
    }
}

// x (fp32, N x 64) -> xb (bf16, N x 64)
__global__ void xconv_kernel(const float* __restrict__ x, ushort_t* __restrict__ xb, int total16) {
    int idx = blockIdx.x * blockDim.x + threadIdx.x;
    if (idx >= total16) return;
    float4 v = *(const float4*)&x[(size_t)idx * 4];
    ushort4 u;
    u.x = f2b(v.x); u.y = f2b(v.y); u.z = f2b(v.z); u.w = f2b(v.w);
    *(ushort4*)&xb[(size_t)idx * 4] = u;
}

// gout folding: Fl = gout_w @ wl_bot, Fr = gout_w @ wr_bot (fp32),
// bias2 = s0_b + gout_b @ wl_bot, cvec = gout_b @ wr_bot.
__global__ void foldw_kernel(const float* __restrict__ gw, const float* __restrict__ gb,
                             const float* __restrict__ s0wl, const float* __restrict__ s0wr,
                             const float* __restrict__ s0bias,
                             float* __restrict__ Fl, float* __restrict__ Fr,
                             float* __restrict__ bias2, float* __restrict__ cvec) {
    int idx = blockIdx.x * blockDim.x + threadIdx.x;   // 128*256
    if (idx >= 128 * 256) return;
    int k = idx >> 8, n = idx & 255;
    const float* wl = s0wl + 64 * 256;   // rows 64..191
    const float* wr = s0wr + 64 * 256;
    float al = 0.f, ar = 0.f;
    for (int j = 0; j < 128; ++j) {
        float g = gw[k * 128 + j];
        al += g * wl[j * 256 + n];
        ar += g * wr[j * 256 + n];
    }
    Fl[k * 256 + n] = al;
    Fr[k * 256 + n] = ar;
    if (k == 0) {
        float bl = 0.f, br = 0.f;
        for (int j = 0; j < 128; ++j) {
            float g = gb[j];
            bl += g * wl[j * 256 + n];
            br += g * wr[j * 256 + n];
        }
        bias2[n] = s0bias[n] + bl;
        cvec[n] = br;
    }
}

// ---------------------------------------------------------------------------
// Weight convert + pack into MFMA fragment order.
// off = ((n>>4)*(K>>5) + (k>>5))*512 + ((n&15)|(((k>>3)&3)<<4))*8 + (k&7)
// ---------------------------------------------------------------------------
struct WtDesc { const float* src; ushort_t* dst; int lk2; int K; int N; int base; };
struct WtArgs { WtDesc d[10]; int total; };
__global__ void wtconv_kernel(WtArgs a) {
    int idx = blockIdx.x * blockDim.x + threadIdx.x;
    if (idx >= a.total) return;
    int s = 0;
#pragma unroll
    for (int i = 1; i < 10; ++i) if (idx >= a.d[i].base) s = i;
    int local = idx - a.d[s].base;
    int K = a.d[s].K;
    int n = local >> a.d[s].lk2;
    int k = local & (K - 1);
    unsigned off = (unsigned)((n >> 4) * (K >> 5) + (k >> 5)) * 512u
                 + (unsigned)(((n & 15) | (((k >> 3) & 3) << 4)) << 3) + (unsigned)(k & 7);
    a.d[s].dst[off] = f2b(a.d[s].src[(size_t)k * a.d[s].N + n]);
}

// ---------------------------------------------------------------------------
// bf16 gather aggregation: one wave per node, lane handles VEC bf16.
// MODE 0: out[i] = h[i] + sum_nbr h[j]   MODE 1: out[i] = invdeg[i]*sum h[j]
// Wave-uniform rowptr bounds via readfirstlane -> scalar col loads.
// ---------------------------------------------------------------------------
template <int VEC>
__device__ __forceinline__ void ldrow(const ushort_t* p, float* t) {
    if constexpr (VEC == 1) {
        t[0] = b2f(p[0]);
    } else if constexpr (VEC == 2) {
        unsigned int v = *(const unsigned int*)p;
        t[0] = b2f(v & 0xffffu); t[1] = b2f(v >> 16);
    } else {
        uint2 v = *(const uint2*)p;
        t[0] = b2f(v.x & 0xffffu); t[1] = b2f(v.x >> 16);
        t[2] = b2f(v.y & 0xffffu); t[3] = b2f(v.y >> 16);
    }
}

template <int VEC, int MODE>
__global__ __launch_bounds__(256) void aggb_kernel(
    const ushort_t* __restrict__ h, int ldh,
    const int* __restrict__ rowptr, const int* __restrict__ col,
    const float* __restrict__ invdeg,
    ushort_t* __restrict__ out, int ldo, int Nn, int lanes) {
    int wid = blockIdx.x * 4 + ((int)threadIdx.x >> 6);
    int lane = (int)threadIdx.x & 63;
    if (wid >= Nn || lane >= lanes) return;

    const ushort_t* hb = h + (size_t)lane * VEC;
    float a[VEC], b2a[VEC];
#pragma unroll
    for (int v = 0; v < VEC; ++v) { a[v] = 0.f; b2a[v] = 0.f; }

    int p0 = __builtin_amdgcn_readfirstlane(rowptr[wid]);
    int p1 = __builtin_amdgcn_readfirstlane(rowptr[wid + 1]);
    int p = p0;
    for (; p + 8 <= p1; p += 8) {
        int j0 = col[p], j1 = col[p + 1], j2 = col[p + 2], j3 = col[p + 3];
        int j4 = col[p + 4], j5 = col[p + 5], j6 = col[p + 6], j7 = col[p + 7];
        float t0[VEC], t1[VEC], t2[VEC], t3[VEC], t4[VEC], t5[VEC], t6[VEC], t7[VEC];
        ldrow<VEC>(hb + (size_t)j0 * ldh, t0);
        ldrow<VEC>(hb + (size_t)j1 * ldh, t1);
        ldrow<VEC>(hb + (size_t)j2 * ldh, t2);
        ldrow<VEC>(hb + (size_t)j3 * ldh, t3);
        ldrow<VEC>(hb + (size_t)j4 * ldh, t4);
        ldrow<VEC>(hb + (size_t)j5 * ldh, t5);
        ldrow<VEC>(hb + (size_t)j6 * ldh, t6);
        ldrow<VEC>(hb + (size_t)j7 * ldh, t7);
#pragma unroll
        for (int v = 0; v < VEC; ++v) {
            a[v]  += (t0[v] + t1[v]) + (t2[v] + t3[v]);
            b2a[v] += (t4[v] + t5[v]) + (t6[v] + t7[v]);
        }
    }
    for (; p + 4 <= p1; p += 4) {
        int j0 = col[p], j1 = col[p + 1], j2 = col[p + 2], j3 = col[p + 3];
        float t0[VEC], t1[VEC], t2[VEC], t3[VEC];
        ldrow<VEC>(hb + (size_t)j0 * ldh, t0);
        ldrow<VEC>(hb + (size_t)j1 * ldh, t1);
        ldrow<VEC>(hb + (size_t)j2 * ldh, t2);
        ldrow<VEC>(hb + (size_t)j3 * ldh, t3);
#pragma unroll
        for (int v = 0; v < VEC; ++v) a[v] += (t0[v] + t1[v]) + (t2[v] + t3[v]);
    }
    for (; p < p1; ++p) {
        float t[VEC];
        ldrow<VEC>(hb + (size_t)col[p] * ldh, t);
#pragma unroll
        for (int v = 0; v < VEC; ++v) a[v] += t[v];
    }
#pragma unroll
    for (int v = 0; v < VEC; ++v) a[v] += b2a[v];

    if constexpr (MODE == 0) {
        float t[VEC];
        ldrow<VEC>(hb + (size_t)wid * ldh, t);
#pragma unroll
        for (int v = 0; v < VEC; ++v) a[v] += t[v];
    } else {
        float s = invdeg[wid];
#pragma unroll
        for (int v = 0; v < VEC; ++v) a[v] *= s;
    }

    ushort_t* op = out + (size_t)wid * ldo + (size_t)lane * VEC;
    if constexpr (VEC == 1) {
        op[0] = f2b(a[0]);
    } else if constexpr (VEC == 2) {
        unsigned int v = (unsigned int)f2b(a[0]) | ((unsigned int)f2b(a[1]) << 16);
        *(unsigned int*)op = v;
    } else {
        uint2 v;
        v.x = (unsigned int)f2b(a[0]) | ((unsigned int)f2b(a[1]) << 16);
        v.y = (unsigned int)f2b(a[2]) | ((unsigned int)f2b(a[3]) << 16);
        *(uint2*)op = v;
    }
}

// Merged x-gather: out32 = GIN-0 input (32-wide), out64 = mean1-x (64-wide)
__global__ __launch_bounds__(256) void aggdual_kernel(
    const ushort_t* __restrict__ xb,
    const int* __restrict__ rowptr, const int* __restrict__ col,
    const float* __restrict__ invdeg,
    ushort_t* __restrict__ out32, ushort_t* __restrict__ out64, int Nn) {
    int wid = blockIdx.x * 4 + ((int)threadIdx.x >> 6);
    int lane = (int)threadIdx.x & 63;
    if (wid >= Nn) return;
    const ushort_t* hb = xb + lane;
    float a = 0.f, b2a = 0.f;
    int p0 = __builtin_amdgcn_readfirstlane(rowptr[wid]);
    int p1 = __builtin_amdgcn_readfirstlane(rowptr[wid + 1]);
    int p = p0;
    for (; p + 8 <= p1; p += 8) {
        float v0 = b2f(hb[(size_t)col[p] * 64]);
        float v1 = b2f(hb[(size_t)col[p + 1] * 64]);
        float v2 = b2f(hb[(size_t)col[p + 2] * 64]);
        float v3 = b2f(hb[(size_t)col[p + 3] * 64]);
        float v4 = b2f(hb[(size_t)col[p + 4] * 64]);
        float v5 = b2f(hb[(size_t)col[p + 5] * 64]);
        float v6 = b2f(hb[(size_t)col[p + 6] * 64]);
        float v7 = b2f(hb[(size_t)col[p + 7] * 64]);
        a += (v0 + v1) + (v2 + v3);
        b2a += (v4 + v5) + (v6 + v7);
    }
    for (; p + 4 <= p1; p += 4) {
        float v0 = b2f(hb[(size_t)col[p] * 64]);
        float v1 = b2f(hb[(size_t)col[p + 1] * 64]);
        float v2 = b2f(hb[(size_t)col[p + 2] * 64]);
        float v3 = b2f(hb[(size_t)col[p + 3] * 64]);
        a += (v0 + v1) + (v2 + v3);
    }
    for (; p < p1; ++p) a += b2f(hb[(size_t)col[p] * 64]);
    a += b2a;
    out64[(size_t)wid * 64 + lane] = f2b(a * invdeg[wid]);
    if (lane < 32) {
        float self = b2f(hb[(size_t)wid * 64]);
        out32[(size_t)wid * 32 + lane] = f2b(a + self);
    }
}

// ---------------------------------------------------------------------------
// Chain-fused bf16 MFMA GEMM (R16 version, codegen-clean: no projection path).
// Tlds fragment layout: [chunk][rowgrp(4)][lane(64)][8 bf16] (16 KB).
// W slab staged via async global->LDS; W2 register-prefetched.
// ---------------------------------------------------------------------------
struct GPass { const ushort_t* A; const ushort_t* Wp; int lda; int K; };
struct FArgs {
    GPass p[4]; int np;
    const ushort_t* W2p;                         // chain==2 second GEMM W
    const float* b1; const float* b2;
    int relu1, relu2;
    int chain;                                   // 1..2
    const float* rowmask; const float* cvec;     // optional rank-1 term
};

__global__ __launch_bounds__(512) void fgemm_kernel(
    FArgs fa, int M, ushort_t* __restrict__ out, int ldc) {
    __shared__ __align__(16) ushort_t Tlds[8192];          // 16 KB
    __shared__ __align__(16) ushort_t Wlds[16384];         // 32 KB

    int rowbase = blockIdx.x * 64;
    int colbase = blockIdx.y * 128;
    int tid = threadIdx.x;
    int lane = tid & 63, w = tid >> 6;           // 8 waves
    int wr3 = w & 3, wc2 = w >> 2;
    int lr = lane & 15, rq = (lane >> 4) * 4;

    f32x4 acc[4];
#pragma unroll
    for (int j = 0; j < 4; ++j) acc[j] = (f32x4){0.f, 0.f, 0.f, 0.f};

    u32x4 w2a = (u32x4){0u,0u,0u,0u}, w2b = w2a, w2c = w2a, w2d = w2a;

    for (int q = 0; q < fa.np; ++q) {
        const ushort_t* A = fa.p[q].A;
        const ushort_t* Wp = fa.p[q].Wp;
        int lda = fa.p[q].lda, K = fa.p[q].K;
        int nch = K >> 5;

        // async stage W slab: nch*512 uint4s, lane-contiguous
        {
            const ushort_t* wsrc = &Wp[((size_t)(colbase >> 4) * nch) * 512];
            for (int j = 0; j < nch; ++j) {
                int i = w * 64 + j * 512;        // wave-uniform uint4 base
                gload_lds16(wsrc + (size_t)(i + lane) * 8, &Wlds[i * 8]);
            }
        }
        // async stage A tile: subtile (c, rgrp) per wave-iteration, 16B/lane
        for (int s = w; s < nch * 4; s += 8) {
            int c = s >> 2, rgrp = s & 3;
            int gr = rowbase + rgrp * 16 + lr;
            int gcol = c * 32 + (lane >> 4) * 8;
            if (gr < M)
                gload_lds16(&A[(size_t)gr * lda + gcol], &Tlds[c * 2048 + rgrp * 512]);
        }
        // prefetch chain W2 into static registers (latency hides under GEMM1)
        if (q == 0 && fa.chain >= 2) {
            const u32x4* w2src = (const u32x4*)fa.W2p;
            w2a = w2src[tid];
            w2b = w2src[tid + 512];
            w2c = w2src[tid + 1024];
            w2d = w2src[tid + 1536];
        }
        __syncthreads();
        int cgl0 = wc2 * 4;
        for (int c = 0; c < nch; ++c) {
            bf16x8 af = *(const bf16x8*)&Tlds[c * 2048 + wr3 * 512 + lane * 8];
            bf16x8 bfr[4];
#pragma unroll
            for (int j = 0; j < 4; ++j)
                bfr[j] = *(const bf16x8*)&Wlds[(((cgl0 + j) * nch) + c) * 512 + lane * 8];
#pragma unroll
            for (int j = 0; j < 4; ++j)
                acc[j] = __builtin_amdgcn_mfma_f32_16x16x32_bf16(af, bfr[j], acc[j], 0, 0, 0);
        }
        __syncthreads();
    }

    if (fa.chain >= 2) {
        // W2 from registers -> LDS (no global latency here)
        ((u32x4*)Wlds)[tid] = w2a;
        ((u32x4*)Wlds)[tid + 512] = w2b;
        ((u32x4*)Wlds)[tid + 1024] = w2c;
        ((u32x4*)Wlds)[tid + 1536] = w2d;
        // epilogue of GEMM1 -> Tlds in fragment layout (A2[row][k=colj])
#pragma unroll
        for (int j = 0; j < 4; ++j) {
            int colj = wc2 * 64 + j * 16 + lr;
            float bv = fa.b1[colj];
            int kk = colj & 31;
            int cof = (colj >> 5) * 2048 + ((((kk >> 3) << 4)) << 3) + (kk & 7);
#pragma unroll
            for (int t = 0; t < 4; ++t) {
                int row = wr3 * 16 + rq + t;
                float v = acc[j][t] + bv;
                if (fa.relu1) v = fmaxf(v, 0.f);
                Tlds[cof + wr3 * 512 + ((row & 15) << 3)] = f2b(v);
            }
            acc[j] = (f32x4){0.f, 0.f, 0.f, 0.f};
        }
        __syncthreads();
        int cgl0 = wc2 * 4;
        for (int c = 0; c < 4; ++c) {
            bf16x8 af = *(const bf16x8*)&Tlds[c * 2048 + wr3 * 512 + lane * 8];
            bf16x8 bfr[4];
#pragma unroll
            for (int j = 0; j < 4; ++j)
                bfr[j] = *(const bf16x8*)&Wlds[((cgl0 + j) * 4 + c) * 512 + lane * 8];
#pragma unroll
            for (int j = 0; j < 4; ++j)
                acc[j] = __builtin_amdgcn_mfma_f32_16x16x32_bf16(af, bfr[j], acc[j], 0, 0, 0);
        }
        __syncthreads();
    }

    const float* bf_ = (fa.chain == 1) ? fa.b1 : fa.b2;
    int reluf = (fa.chain == 1) ? fa.relu1 : fa.relu2;
    float rm[4];
#pragma unroll
    for (int t = 0; t < 4; ++t) {
        int gr = rowbase + wr3 * 16 + rq + t;
        rm[t] = (fa.cvec && gr < M) ? fa.rowmask[gr] : 0.f;
    }
#pragma unroll
    for (int j = 0; j < 4; ++j) {
        int colj = wc2 * 64 + j * 16 + lr;
        float bv = bf_[colbase + colj];
        float cv = fa.cvec ? fa.cvec[colbase + colj] : 0.f;
#pragma unroll
        for (int t = 0; t < 4; ++t) {
            int row = wr3 * 16 + rq + t;
            float v = acc[j][t] + bv + rm[t] * cv;
            if (reluf) v = fmaxf(v, 0.f);
            Tlds[row * 128 + colj] = f2b(v);
        }
    }
    __syncthreads();
    for (int u = tid; u < 1024; u += 512) {
        int row = u >> 4, seg = u & 15;
        int gr = rowbase + row;
        if (gr < M)
            *(u32x4*)&out[(size_t)gr * ldc + colbase + seg * 8] =
                *(const u32x4*)&Tlds[row * 128 + seg * 8];
    }
}

// ---------------------------------------------------------------------------
// s0 GEMM + in-register projection (separate kernel so the chain fgemm's
// codegen is unperturbed). np=4 passes, chain=1, rank-1 term, projection
// epilogue: per-row dots onto pwl/pwr, shfl_xor reduce, fp32 atomicAdd.
// ---------------------------------------------------------------------------
struct PArgs {
    GPass p[4];
    const float* b1;
    const float* rowmask; const float* cvec;
    const float* pwl; const float* pwr;
    float* pzl; float* pz;
};

__global__ __launch_bounds__(512) void fgemm_proj_kernel(PArgs fa, int M) {
    __shared__ __align__(16) ushort_t Tlds[8192];          // 16 KB
    __shared__ __align__(16) ushort_t Wlds[16384];         // 32 KB

    int rowbase = blockIdx.x * 64;
    int colbase = blockIdx.y * 128;
    int tid = threadIdx.x;
    int lane = tid & 63, w = tid >> 6;
    int wr3 = w & 3, wc2 = w >> 2;
    int lr = lane & 15, rq = (lane >> 4) * 4;

    f32x4 acc[4];
#pragma unroll
    for (int j = 0; j < 4; ++j) acc[j] = (f32x4){0.f, 0.f, 0.f, 0.f};

    for (int q = 0; q < 4; ++q) {
        const ushort_t* A = fa.p[q].A;
        const ushort_t* Wp = fa.p[q].Wp;
        int lda = fa.p[q].lda, K = fa.p[q].K;
        int nch = K >> 5;
        {
            const ushort_t* wsrc = &Wp[((size_t)(colbase >> 4) * nch) * 512];
            for (int j = 0; j < nch; ++j) {
                int i = w * 64 + j * 512;
                gload_lds16(wsrc + (size_t)(i + lane) * 8, &Wlds[i * 8]);
            }
        }
        for (int s = w; s < nch * 4; s += 8) {
            int c = s >> 2, rgrp = s & 3;
            int gr = rowbase + rgrp * 16 + lr;
            int gcol = c * 32 + (lane >> 4) * 8;
            if (gr < M)
                gload_lds16(&A[(size_t)gr * lda + gcol], &Tlds[c * 2048 + rgrp * 512]);
        }
        __syncthreads();
        int cgl0 = wc2 * 4;
        for (int c = 0; c < nch; ++c) {
            bf16x8 af = *(const bf16x8*)&Tlds[c * 2048 + wr3 * 512 + lane * 8];
            bf16x8 bfr[4];
#pragma unroll
            for (int j = 0; j < 4; ++j)
                bfr[j] = *(const bf16x8*)&Wlds[(((cgl0 + j) * nch) + c) * 512 + lane * 8];
#pragma unroll
            for (int j = 0; j < 4; ++j)
                acc[j] = __builtin_amdgcn_mfma_f32_16x16x32_bf16(af, bfr[j], acc[j], 0, 0, 0);
        }
        __syncthreads();
    }

    float rm[4];
#pragma unroll
    for (int t = 0; t < 4; ++t) {
        int gr = rowbase + wr3 * 16 + rq + t;
        rm[t] = (gr < M) ? fa.rowmask[gr] : 0.f;
    }
    float part[4][4];
#pragma unroll
    for (int t = 0; t < 4; ++t)
#pragma unroll
        for (int k = 0; k < 4; ++k) part[t][k] = 0.f;
#pragma unroll
    for (int j = 0; j < 4; ++j) {
        int c = colbase + wc2 * 64 + j * 16 + lr;
        float bv = fa.b1[c];
        float cv = fa.cvec[c];
        float wl0 = fa.pwl[2 * c], wl1 = fa.pwl[2 * c + 1];
        float wr0 = fa.pwr[2 * c], wr1 = fa.pwr[2 * c + 1];
#pragma unroll
        for (int t = 0; t < 4; ++t) {
            float v = fmaxf(acc[j][t] + bv + rm[t] * cv, 0.f);
            part[t][0] += v * wl0;
            part[t][1] += v * wl1;
            part[t][2] += v * wr0;
            part[t][3] += v * wr1;
        }
    }
#pragma unroll
    for (int t = 0; t < 4; ++t)
#pragma unroll
        for (int k = 0; k < 4; ++k) {
            float s = part[t][k];
            s += __shfl_xor(s, 1);
            s += __shfl_xor(s, 2);
            s += __shfl_xor(s, 4);
            s += __shfl_xor(s, 8);
            part[t][k] = s;
        }
    if (lr == 0) {
#pragma unroll
        for (int t = 0; t < 4; ++t) {
            int gr = rowbase + wr3 * 16 + rq + t;
            if (gr < M) {
                atomicAdd(&fa.pzl[2 * gr], part[t][0]);
                atomicAdd(&fa.pzl[2 * gr + 1], part[t][1]);
                atomicAdd(&fa.pz[2 * gr], part[t][2]);
                atomicAdd(&fa.pz[2 * gr + 1], part[t][3]);
            }
        }
    }
}

// out[i] = zl[i] + invdeg[i] * sum_nbr z[j] + b ; one thread per node
__global__ void aggz_kernel(const float2* __restrict__ z, const float2* __restrict__ zl,
                            const int* __restrict__ rowptr, const int* __restrict__ col,
                            const float* __restrict__ invdeg, const float* __restrict__ b,
                            float* __restrict__ out, int Nn) {
    int i = blockIdx.x * blockDim.x + threadIdx.x;
    if (i >= Nn) return;
    float s0 = 0.f, s1 = 0.f;
    int p = rowptr[i], p1 = rowptr[i + 1];
    for (; p + 4 <= p1; p += 4) {
        float2 a = z[col[p]], c = z[col[p + 1]], d = z[col[p + 2]], e = z[col[p + 3]];
        s0 += (a.x + c.x) + (d.x + e.x);
        s1 += (a.y + c.y) + (d.y + e.y);
    }
    for (; p < p1; ++p) {
        float2 a = z[col[p]];
        s0 += a.x; s1 += a.y;
    }
    float inv = invdeg[i];
    float2 l = zl[i];
    out[(size_t)i * 2 + 0] = l.x + inv * s0 + b[0];
    out[(size_t)i * 2 + 1] = l.y + inv * s1 + b[1];
}

extern "C" void kernel_launch(void* const* d_in, const int* in_sizes, int n_in,
                              void* d_out, int out_size, void* d_ws, size_t ws_size,
                              hipStream_t stream) {
    const float* x      = (const float*)d_in[0];
    const int*   ei     = (const int*)d_in[1];
    const float* g_w1[3] = {(const float*)d_in[2], (const float*)d_in[6],  (const float*)d_in[10]};
    const float* g_b1[3] = {(const float*)d_in[3], (const float*)d_in[7],  (const float*)d_in[11]};
    const float* g_w2[3] = {(const float*)d_in[4], (const float*)d_in[8],  (const float*)d_in[12]};
    const float* g_b2[3] = {(const float*)d_in[5], (const float*)d_in[9],  (const float*)d_in[13]};
    const float* gout_w = (const float*)d_in[14];
    const float* gout_b = (const float*)d_in[15];
    const float* s0_wl  = (const float*)d_in[16];
    const float* s0_wr  = (const float*)d_in[17];
    const float* s0_b   = (const float*)d_in[18];
    const float* s1_wl  = (const float*)d_in[19];
    const float* s1_wr  = (const float*)d_in[20];
    const float* s1_b   = (const float*)d_in[21];
    float* out = (float*)d_out;

    const int N = in_sizes[0] / 64;
    const int E = in_sizes[1] / 2;

    char* ws = (char*)d_ws;
    size_t o = 0;
    auto take = [&](size_t bytes) -> char* {
        char* p = ws + o;
        o = (o + bytes + 255) & ~(size_t)255;
        return p;
    };
    ushort_t* xb     = (ushort_t*)take((size_t)N * 64 * 2);
    ushort_t* bA     = (ushort_t*)take((size_t)N * 128 * 2);
    ushort_t* bB     = (ushort_t*)take((size_t)N * 128 * 2);
    ushort_t* bC     = (ushort_t*)take((size_t)N * 128 * 2);
    ushort_t* aggxb  = (ushort_t*)take((size_t)N * 64 * 2);
    ushort_t* agggb  = (ushort_t*)take((size_t)N * 128 * 2);
    float2*   zlb    = (float2*)take((size_t)N * 2 * 4);
    float2*   zb     = (float2*)take((size_t)N * 2 * 4);
    float* Flbuf = (float*)take(128 * 256 * 4);
    float* Frbuf = (float*)take(128 * 256 * 4);
    float* bias2 = (float*)take(256 * 4);
    float* cvecb = (float*)take(256 * 4);
    ushort_t* w1t0 = (ushort_t*)take(128 * 32 * 2);
    ushort_t* w2t0 = (ushort_t*)take(128 * 128 * 2);
    ushort_t* w1t1 = (ushort_t*)take(128 * 128 * 2);
    ushort_t* w2t1 = (ushort_t*)take(128 * 128 * 2);
    ushort_t* w1t2 = (ushort_t*)take(128 * 128 * 2);
    ushort_t* w2t2 = (ushort_t*)take(128 * 128 * 2);
    ushort_t* wltop = (ushort_t*)take(256 * 64 * 2);
    ushort_t* wglp  = (ushort_t*)take(256 * 128 * 2);
    ushort_t* wrtop = (ushort_t*)take(256 * 64 * 2);
    ushort_t* wgrp  = (ushort_t*)take(256 * 128 * 2);
    unsigned* stage  = (unsigned*)take((size_t)E * 4);
    int*   colI   = (int*)take((size_t)E * 4);
    int*   rowptr = (int*)take((size_t)(N + 1) * 4);
    int*   deg    = (int*)take((size_t)N * 4);
    float* invdeg = (float*)take((size_t)N * 4);
    float* maskb  = (float*)take((size_t)N * 4);
    int*   blocksum = (int*)take(256 * 4);
    int*   blockoff = (int*)take(256 * 4);
    int*   bucket_cursor = (int*)take(512 * 4);
    int*   flag   = (int*)take(4);

    hipMemsetAsync(deg, 0, (size_t)N * 4, stream);
    hipMemsetAsync(flag, 1, 4, stream);
    hipMemsetAsync(zlb, 0, (size_t)N * 2 * 4, stream);
    hipMemsetAsync(zb, 0, (size_t)N * 2 * 4, stream);

    const int TB = 256;
    const int nb = (N + 2047) / 2048;
    const int NBKT = (N + 255) >> 8;

    // --- CSR by dst: deg -> scan -> binned two-phase build ---
    detect_kernel<<<4, TB, 0, stream>>>(ei, 1024, flag);
    deg_kernel<<<(E + TB - 1) / TB, TB, 0, stream>>>(ei, E, flag, deg);
    scanA_kernel<<<nb, 256, 0, stream>>>(deg, N, rowptr, blocksum);
    scanB_kernel<<<1, 256, 0, stream>>>(blocksum, nb, blockoff, rowptr, N);
    scanC_kernel<<<(N + TB - 1) / TB, TB, 0, stream>>>(deg, N, blockoff, rowptr, invdeg, maskb, bucket_cursor);
    binA_kernel<<<(E + 4095) / 4096, 256, 0, stream>>>(ei, E, flag, bucket_cursor, stage);
    binB_kernel<<<NBKT, 256, 0, stream>>>(stage, rowptr, N, colI);

    // --- gout fold (fp32) + weight convert/pack ---
    foldw_kernel<<<128, 256, 0, stream>>>(gout_w, gout_b, s0_wl, s0_wr, s0_b,
                                          Flbuf, Frbuf, bias2, cvecb);
    WtArgs wa;
    const float* wsrc[10] = {g_w1[0], g_w2[0], g_w1[1], g_w2[1], g_w1[2], g_w2[2],
                             s0_wl, Flbuf, s0_wr, Frbuf};
    ushort_t* wdst[10]    = {w1t0, w2t0, w1t1, w2t1, w1t2, w2t2,
                             wltop, wglp, wrtop, wgrp};
    int wk[10]  = {32, 128, 128, 128, 128, 128, 64, 128, 64, 128};
    int wl2[10] = {5, 7, 7, 7, 7, 7, 6, 7, 6, 7};
    int wn[10]  = {128, 128, 128, 128, 128, 128, 256, 256, 256, 256};
    int base = 0;
    for (int i = 0; i < 10; ++i) {
        wa.d[i].src = wsrc[i]; wa.d[i].dst = wdst[i];
        wa.d[i].lk2 = wl2[i]; wa.d[i].K = wk[i]; wa.d[i].N = wn[i]; wa.d[i].base = base;
        base += wk[i] * wn[i];
    }
    wa.total = base;
    wtconv_kernel<<<(base + TB - 1) / TB, TB, 0, stream>>>(wa);

    // --- x -> bf16 ---
    xconv_kernel<<<((N * 16) + TB - 1) / TB, TB, 0, stream>>>(x, xb, N * 16);

    const int AGG_GRID = (N + 3) / 4;
    const int GX = (N + 63) / 64;

    // merged x-gather: bB = GIN-0 input (32-wide), aggxb = mean1-x (64-wide)
    aggdual_kernel<<<AGG_GRID, 256, 0, stream>>>(xb, rowptr, colI, invdeg, bB, aggxb, N);

    // --- GIN layer 0 (chain=2): bB -> h1 = bA ---
    {
        FArgs fa = {};
        fa.p[0] = {bB, w1t0, 32, 32};
        fa.np = 1;
        fa.W2p = w2t0;
        fa.b1 = g_b1[0]; fa.b2 = g_b2[0];
        fa.relu1 = 1; fa.relu2 = 1;
        fa.chain = 2;
        fgemm_kernel<<<dim3(GX, 1), 512, 0, stream>>>(fa, N, bA, 128);
    }

    // --- GIN layer 1: bA -> agg bB -> h2 = bC ---
    aggb_kernel<2, 0><<<AGG_GRID, 256, 0, stream>>>(bA, 128, rowptr, colI, invdeg, bB, 128, N, 64);
    {
        FArgs fa = {};
        fa.p[0] = {bB, w1t1, 128, 128};
        fa.np = 1;
        fa.W2p = w2t1;
        fa.b1 = g_b1[1]; fa.b2 = g_b2[1];
        fa.relu1 = 1; fa.relu2 = 1;
        fa.chain = 2;
        fgemm_kernel<<<dim3(GX, 1), 512, 0, stream>>>(fa, N, bC, 128);
    }

    // --- GIN layer 2 (chain=2): bC -> agg bB -> h3 = bA ---
    aggb_kernel<2, 0><<<AGG_GRID, 256, 0, stream>>>(bC, 128, rowptr, colI, invdeg, bB, 128, N, 64);
    {
        FArgs fa = {};
        fa.p[0] = {bB, w1t2, 128, 128};
        fa.np = 1;
        fa.W2p = w2t2;
        fa.b1 = g_b1[2]; fa.b2 = g_b2[2];
        fa.relu1 = 1; fa.relu2 = 1;
        fa.chain = 2;
        fgemm_kernel<<<dim3(GX, 1), 512, 0, stream>>>(fa, N, bA, 128);
    }

    // mean-agg(h3) (gout folded into s0 weights)
    aggb_kernel<2, 1><<<AGG_GRID, 256, 0, stream>>>(bA, 128, rowptr, colI, invdeg, agggb, 128, N, 64);

    // s0 = relu(x@wltop + h3@Fl + aggx@wrtop + aggh3@Fr + bias2 + mask.cvec),
    // fused with projection onto s1_wl/s1_wr (writes zl, z; never materializes s0)
    {
        PArgs fa = {};
        fa.p[0] = {xb, wltop, 64, 64};
        fa.p[1] = {bA, wglp, 128, 128};
        fa.p[2] = {aggxb, wrtop, 64, 64};
        fa.p[3] = {agggb, wgrp, 128, 128};
        fa.b1 = bias2;
        fa.rowmask = maskb; fa.cvec = cvecb;
        fa.pwl = s1_wl; fa.pwr = s1_wr;
        fa.pzl = (float*)zlb; fa.pz = (float*)zb;
        fgemm_proj_kernel<<<dim3(GX, 2), 512, 0, stream>>>(fa, N);
    }

    // out = zl + invdeg * agg(z) + b
    aggz_kernel<<<(N + TB - 1) / TB, TB, 0, stream>>>(zb, zlb, rowptr, colI, invdeg, s1_b, out, N);
}

// Round 21
// 306.267 us; speedup vs baseline: 1.0680x; 1.0449x over previous
//
#include <hip/hip_runtime.h>

// ---------------------------------------------------------------------------
// GAMLNET GNN forward, bf16 edition, R20.
// R20 = R19 with the partials-indexing bug fixed: each output row is written
// by TWO waves (wc2=0: cols 0-63, wc2=1: cols 64-127) per y-block; R19
// indexed partials only by blockIdx.y so one overwrote the other. Partials
// are now [blockIdx.y*2 + wc2][row] (4 slices) and combine sums all four.
// NOTE: edge packing assumes N <= 65536 (problem fixes N=50000).
// ---------------------------------------------------------------------------

typedef unsigned short ushort_t;
typedef __bf16 bf16x8 __attribute__((ext_vector_type(8)));
typedef float f32x4 __attribute__((ext_vector_type(4)));
typedef unsigned u32x4 __attribute__((ext_vector_type(4)));

__device__ __forceinline__ float b2f(unsigned int u16) {
    union { unsigned int i; float f; } v;
    v.i = u16 << 16;
    return v.f;
}
__device__ __forceinline__ unsigned short f2b(float f) {
    union { float f; unsigned int i; } v;
    v.f = f;
    unsigned int x = v.i;
    unsigned int r = (x + 0x7fffu + ((x >> 16) & 1u)) >> 16;  // RNE
    return (unsigned short)r;
}

// async 16-byte global -> LDS copy (lane-level; LDS dest = uniform base + lane*16)
__device__ __forceinline__ void gload_lds16(const void* g, void* l) {
    __builtin_amdgcn_global_load_lds(
        (const __attribute__((address_space(1))) unsigned int*)g,
        (__attribute__((address_space(3))) unsigned int*)l,
        16, 0, 0);
}

// --- edge dtype detection: if input is int64, odd int32 words are all zero ---
__global__ void detect_kernel(const int* __restrict__ ei, int ncheck, int* flag) {
    int t = blockIdx.x * blockDim.x + threadIdx.x;
    if (t < ncheck) {
        if (ei[2 * t + 1] != 0) atomicAnd(flag, 0);
    }
}

// deg count straight from edge_index (flag-branched layout)
__global__ void deg_kernel(const int* __restrict__ ei, int E, const int* __restrict__ flag,
                           int* __restrict__ deg) {
    int e = blockIdx.x * blockDim.x + threadIdx.x;
    if (e >= E) return;
    int d = (*flag) ? ei[2 * ((size_t)E + e)] : ei[(size_t)E + e];
    atomicAdd(&deg[d], 1);
}

// --- 3-phase multi-block exclusive scan (2048 elements per block) ---
__global__ __launch_bounds__(256) void scanA_kernel(const int* __restrict__ deg, int n,
                                                    int* __restrict__ rowptr,
                                                    int* __restrict__ blocksum) {
    __shared__ int sh[256];
    int b = blockIdx.x, tid = threadIdx.x;
    int base = b * 2048 + tid * 8;
    int v[8];
#pragma unroll
    for (int e = 0; e < 8; ++e) {
        int i = base + e;
        v[e] = (i < n) ? deg[i] : 0;
    }
    int t = 0;
#pragma unroll
    for (int e = 0; e < 8; ++e) { int x = v[e]; v[e] = t; t += x; }
    sh[tid] = t;
    __syncthreads();
    for (int off = 1; off < 256; off <<= 1) {
        int val = (tid >= off) ? sh[tid - off] : 0;
        __syncthreads();
        sh[tid] += val;
        __syncthreads();
    }
    int excl = sh[tid] - t;
#pragma unroll
    for (int e = 0; e < 8; ++e) {
        int i = base + e;
        if (i < n) rowptr[i] = excl + v[e];
    }
    if (tid == 255) blocksum[b] = sh[255];
}

__global__ __launch_bounds__(256) void scanB_kernel(const int* __restrict__ blocksum, int nb,
                                                    int* __restrict__ blockoff,
                                                    int* __restrict__ rowptr, int n) {
    __shared__ int sh[256];
    int tid = threadIdx.x;
    int v = (tid < nb) ? blocksum[tid] : 0;
    sh[tid] = v;
    __syncthreads();
    for (int off = 1; off < 256; off <<= 1) {
        int t = (tid >= off) ? sh[tid - off] : 0;
        __syncthreads();
        sh[tid] += t;
        __syncthreads();
    }
    if (tid < nb) blockoff[tid] = sh[tid] - v;
    if (tid == 255) rowptr[n] = sh[255];
}

// finalize rowptr, compute invdeg/mask, and init per-bucket cursors
__global__ void scanC_kernel(const int* __restrict__ deg, int n, const int* __restrict__ blockoff,
                             int* __restrict__ rowptr, float* __restrict__ invdeg,
                             float* __restrict__ mask, int* __restrict__ bucket_cursor) {
    int i = blockIdx.x * blockDim.x + threadIdx.x;
    if (i >= n) return;
    int r = rowptr[i] + blockoff[i >> 11];
    rowptr[i] = r;
    if ((i & 255) == 0) bucket_cursor[i >> 8] = r;
    int d = deg[i];
    invdeg[i] = 1.0f / fmaxf((float)d, 1.0f);
    mask[i] = (d > 0) ? 1.0f : 0.0f;
}

// --- binned CSR phase A: LDS counting-sort of 4096-edge chunks by dst>>8,
//     parallel flush (bucket id packed in bits 24-31). ---
__global__ __launch_bounds__(256) void binA_kernel(
    const int* __restrict__ ei, int E, const int* __restrict__ flag,
    int* __restrict__ bucket_cursor, unsigned* __restrict__ stage) {
    __shared__ unsigned sPair[4096];      // 16 KB
    __shared__ int cnt[256], off[256], gst[256];
    int tid = threadIdx.x;
    cnt[tid] = 0;
    __syncthreads();
    int base = blockIdx.x * 4096;
    bool i64 = (*flag) != 0;
    unsigned u[16];
    int bk[16];
#pragma unroll
    for (int k = 0; k < 16; ++k) {
        int e = base + tid + k * 256;
        if (e < E) {
            int s_, d_;
            if (i64) { s_ = ei[2 * (size_t)e]; d_ = ei[2 * ((size_t)E + e)]; }
            else     { s_ = ei[e];             d_ = ei[(size_t)E + e]; }
            bk[k] = d_ >> 8;
            u[k] = (unsigned)s_ | ((unsigned)(d_ & 255) << 16) | ((unsigned)bk[k] << 24);
            atomicAdd(&cnt[bk[k]], 1);
        } else bk[k] = -1;
    }
    __syncthreads();
    int c = cnt[tid];
    off[tid] = c;
    __syncthreads();
    for (int o = 1; o < 256; o <<= 1) {
        int v = (tid >= o) ? off[tid - o] : 0;
        __syncthreads();
        off[tid] += v;
        __syncthreads();
    }
    int incl = off[tid];
    __syncthreads();
    off[tid] = incl - c;   // exclusive start; advances to end via atomics
    __syncthreads();
#pragma unroll
    for (int k = 0; k < 16; ++k) {
        if (bk[k] >= 0) {
            int p = atomicAdd(&off[bk[k]], 1);
            sPair[p] = u[k];
        }
    }
    if (c > 0) gst[tid] = atomicAdd(&bucket_cursor[tid], c);
    __syncthreads();
    int total = off[255];
    for (int idx = tid; idx < total; idx += 256) {
        unsigned v = sPair[idx];
        int b = (int)(v >> 24);
        int bstart = off[b] - cnt[b];
        stage[gst[b] + (idx - bstart)] = v;
    }
}

// --- binned CSR phase B: one block per bucket, per-node cursors in LDS. ---
__global__ __launch_bounds__(256) void binB_kernel(
    const unsigned* __restrict__ stage, const int* __restrict__ rowptr,
    int Nn, int* __restrict__ col) {
    __shared__ int curs[256];
    int b = blockIdx.x, tid = threadIdx.x;
    int n0 = b << 8;
    if (n0 + tid < Nn) curs[tid] = rowptr[n0 + tid];
    __syncthreads();
    int s = rowptr[n0];
    int e = rowptr[min(n0 + 256, Nn)];
    for (int i = s + tid; i < e; i += 256) {
        unsigned u = stage[i];
        int p = atomicAdd(&curs[(u >> 16) & 255], 1);
        col[p] = (int)(u & 0xffffu);
    }
}

// x (fp32, N x 64) -> xb (bf16, N x 64)
__global__ void xconv_kernel(const float* __restrict__ x, ushort_t* __restrict__ xb, int total16) {
    int idx = blockIdx.x * blockDim.x + threadIdx.x;
    if (idx >= total16) return;
    float4 v = *(const float4*)&x[(size_t)idx * 4];
    ushort4 u;
    u.x = f2b(v.x); u.y = f2b(v.y); u.z = f2b(v.z); u.w = f2b(v.w);
    *(ushort4*)&xb[(size_t)idx * 4] = u;
}

// gout folding: Fl = gout_w @ wl_bot, Fr = gout_w @ wr_bot (fp32),
// bias2 = s0_b + gout_b @ wl_bot, cvec = gout_b @ wr_bot.
__global__ void foldw_kernel(const float* __restrict__ gw, const float* __restrict__ gb,
                             const float* __restrict__ s0wl, const float* __restrict__ s0wr,
                             const float* __restrict__ s0bias,
                             float* __restrict__ Fl, float* __restrict__ Fr,
                             float* __restrict__ bias2, float* __restrict__ cvec) {
    int idx = blockIdx.x * blockDim.x + threadIdx.x;   // 128*256
    if (idx >= 128 * 256) return;
    int k = idx >> 8, n = idx & 255;
    const float* wl = s0wl + 64 * 256;   // rows 64..191
    const float* wr = s0wr + 64 * 256;
    float al = 0.f, ar = 0.f;
    for (int j = 0; j < 128; ++j) {
        float g = gw[k * 128 + j];
        al += g * wl[j * 256 + n];
        ar += g * wr[j * 256 + n];
    }
    Fl[k * 256 + n] = al;
    Fr[k * 256 + n] = ar;
    if (k == 0) {
        float bl = 0.f, br = 0.f;
        for (int j = 0; j < 128; ++j) {
            float g = gb[j];
            bl += g * wl[j * 256 + n];
            br += g * wr[j * 256 + n];
        }
        bias2[n] = s0bias[n] + bl;
        cvec[n] = br;
    }
}

// ---------------------------------------------------------------------------
// Weight convert + pack into MFMA fragment order.
// off = ((n>>4)*(K>>5) + (k>>5))*512 + ((n&15)|(((k>>3)&3)<<4))*8 + (k&7)
// ---------------------------------------------------------------------------
struct WtDesc { const float* src; ushort_t* dst; int lk2; int K; int N; int base; };
struct WtArgs { WtDesc d[10]; int total; };
__global__ void wtconv_kernel(WtArgs a) {
    int idx = blockIdx.x * blockDim.x + threadIdx.x;
    if (idx >= a.total) return;
    int s = 0;
#pragma unroll
    for (int i = 1; i < 10; ++i) if (idx >= a.d[i].base) s = i;
    int local = idx - a.d[s].base;
    int K = a.d[s].K;
    int n = local >> a.d[s].lk2;
    int k = local & (K - 1);
    unsigned off = (unsigned)((n >> 4) * (K >> 5) + (k >> 5)) * 512u
                 + (unsigned)(((n & 15) | (((k >> 3) & 3) << 4)) << 3) + (unsigned)(k & 7);
    a.d[s].dst[off] = f2b(a.d[s].src[(size_t)k * a.d[s].N + n]);
}

// ---------------------------------------------------------------------------
// bf16 gather aggregation: one wave per node, lane handles VEC bf16.
// MODE 0: out[i] = h[i] + sum_nbr h[j]   MODE 1: out[i] = invdeg[i]*sum h[j]
// Wave-uniform rowptr bounds via readfirstlane -> scalar col loads.
// ---------------------------------------------------------------------------
template <int VEC>
__device__ __forceinline__ void ldrow(const ushort_t* p, float* t) {
    if constexpr (VEC == 1) {
        t[0] = b2f(p[0]);
    } else if constexpr (VEC == 2) {
        unsigned int v = *(const unsigned int*)p;
        t[0] = b2f(v & 0xffffu); t[1] = b2f(v >> 16);
    } else {
        uint2 v = *(const uint2*)p;
        t[0] = b2f(v.x & 0xffffu); t[1] = b2f(v.x >> 16);
        t[2] = b2f(v.y & 0xffffu); t[3] = b2f(v.y >> 16);
    }
}

template <int VEC, int MODE>
__global__ __launch_bounds__(256) void aggb_kernel(
    const ushort_t* __restrict__ h, int ldh,
    const int* __restrict__ rowptr, const int* __restrict__ col,
    const float* __restrict__ invdeg,
    ushort_t* __restrict__ out, int ldo, int Nn, int lanes) {
    int wid = blockIdx.x * 4 + ((int)threadIdx.x >> 6);
    int lane = (int)threadIdx.x & 63;
    if (wid >= Nn || lane >= lanes) return;

    const ushort_t* hb = h + (size_t)lane * VEC;
    float a[VEC], b2a[VEC];
#pragma unroll
    for (int v = 0; v < VEC; ++v) { a[v] = 0.f; b2a[v] = 0.f; }

    int p0 = __builtin_amdgcn_readfirstlane(rowptr[wid]);
    int p1 = __builtin_amdgcn_readfirstlane(rowptr[wid + 1]);
    int p = p0;
    for (; p + 8 <= p1; p += 8) {
        int j0 = col[p], j1 = col[p + 1], j2 = col[p + 2], j3 = col[p + 3];
        int j4 = col[p + 4], j5 = col[p + 5], j6 = col[p + 6], j7 = col[p + 7];
        float t0[VEC], t1[VEC], t2[VEC], t3[VEC], t4[VEC], t5[VEC], t6[VEC], t7[VEC];
        ldrow<VEC>(hb + (size_t)j0 * ldh, t0);
        ldrow<VEC>(hb + (size_t)j1 * ldh, t1);
        ldrow<VEC>(hb + (size_t)j2 * ldh, t2);
        ldrow<VEC>(hb + (size_t)j3 * ldh, t3);
        ldrow<VEC>(hb + (size_t)j4 * ldh, t4);
        ldrow<VEC>(hb + (size_t)j5 * ldh, t5);
        ldrow<VEC>(hb + (size_t)j6 * ldh, t6);
        ldrow<VEC>(hb + (size_t)j7 * ldh, t7);
#pragma unroll
        for (int v = 0; v < VEC; ++v) {
            a[v]  += (t0[v] + t1[v]) + (t2[v] + t3[v]);
            b2a[v] += (t4[v] + t5[v]) + (t6[v] + t7[v]);
        }
    }
    for (; p + 4 <= p1; p += 4) {
        int j0 = col[p], j1 = col[p + 1], j2 = col[p + 2], j3 = col[p + 3];
        float t0[VEC], t1[VEC], t2[VEC], t3[VEC];
        ldrow<VEC>(hb + (size_t)j0 * ldh, t0);
        ldrow<VEC>(hb + (size_t)j1 * ldh, t1);
        ldrow<VEC>(hb + (size_t)j2 * ldh, t2);
        ldrow<VEC>(hb + (size_t)j3 * ldh, t3);
#pragma unroll
        for (int v = 0; v < VEC; ++v) a[v] += (t0[v] + t1[v]) + (t2[v] + t3[v]);
    }
    for (; p < p1; ++p) {
        float t[VEC];
        ldrow<VEC>(hb + (size_t)col[p] * ldh, t);
#pragma unroll
        for (int v = 0; v < VEC; ++v) a[v] += t[v];
    }
#pragma unroll
    for (int v = 0; v < VEC; ++v) a[v] += b2a[v];

    if constexpr (MODE == 0) {
        float t[VEC];
        ldrow<VEC>(hb + (size_t)wid * ldh, t);
#pragma unroll
        for (int v = 0; v < VEC; ++v) a[v] += t[v];
    } else {
        float s = invdeg[wid];
#pragma unroll
        for (int v = 0; v < VEC; ++v) a[v] *= s;
    }

    ushort_t* op = out + (size_t)wid * ldo + (size_t)lane * VEC;
    if constexpr (VEC == 1) {
        op[0] = f2b(a[0]);
    } else if constexpr (VEC == 2) {
        unsigned int v = (unsigned int)f2b(a[0]) | ((unsigned int)f2b(a[1]) << 16);
        *(unsigned int*)op = v;
    } else {
        uint2 v;
        v.x = (unsigned int)f2b(a[0]) | ((unsigned int)f2b(a[1]) << 16);
        v.y = (unsigned int)f2b(a[2]) | ((unsigned int)f2b(a[3]) << 16);
        *(uint2*)op = v;
    }
}

// Merged x-gather: out32 = GIN-0 input (32-wide), out64 = mean1-x (64-wide)
__global__ __launch_bounds__(256) void aggdual_kernel(
    const ushort_t* __restrict__ xb,
    const int* __restrict__ rowptr, const int* __restrict__ col,
    const float* __restrict__ invdeg,
    ushort_t* __restrict__ out32, ushort_t* __restrict__ out64, int Nn) {
    int wid = blockIdx.x * 4 + ((int)threadIdx.x >> 6);
    int lane = (int)threadIdx.x & 63;
    if (wid >= Nn) return;
    const ushort_t* hb = xb + lane;
    float a = 0.f, b2a = 0.f;
    int p0 = __builtin_amdgcn_readfirstlane(rowptr[wid]);
    int p1 = __builtin_amdgcn_readfirstlane(rowptr[wid + 1]);
    int p = p0;
    for (; p + 8 <= p1; p += 8) {
        float v0 = b2f(hb[(size_t)col[p] * 64]);
        float v1 = b2f(hb[(size_t)col[p + 1] * 64]);
        float v2 = b2f(hb[(size_t)col[p + 2] * 64]);
        float v3 = b2f(hb[(size_t)col[p + 3] * 64]);
        float v4 = b2f(hb[(size_t)col[p + 4] * 64]);
        float v5 = b2f(hb[(size_t)col[p + 5] * 64]);
        float v6 = b2f(hb[(size_t)col[p + 6] * 64]);
        float v7 = b2f(hb[(size_t)col[p + 7] * 64]);
        a += (v0 + v1) + (v2 + v3);
        b2a += (v4 + v5) + (v6 + v7);
    }
    for (; p + 4 <= p1; p += 4) {
        float v0 = b2f(hb[(size_t)col[p] * 64]);
        float v1 = b2f(hb[(size_t)col[p + 1] * 64]);
        float v2 = b2f(hb[(size_t)col[p + 2] * 64]);
        float v3 = b2f(hb[(size_t)col[p + 3] * 64]);
        a += (v0 + v1) + (v2 + v3);
    }
    for (; p < p1; ++p) a += b2f(hb[(size_t)col[p] * 64]);
    a += b2a;
    out64[(size_t)wid * 64 + lane] = f2b(a * invdeg[wid]);
    if (lane < 32) {
        float self = b2f(hb[(size_t)wid * 64]);
        out32[(size_t)wid * 32 + lane] = f2b(a + self);
    }
}

// ---------------------------------------------------------------------------
// Chain-fused bf16 MFMA GEMM (R16 version, codegen-clean: no projection path).
// Tlds fragment layout: [chunk][rowgrp(4)][lane(64)][8 bf16] (16 KB).
// W slab staged via async global->LDS; W2 register-prefetched.
// ---------------------------------------------------------------------------
struct GPass { const ushort_t* A; const ushort_t* Wp; int lda; int K; };
struct FArgs {
    GPass p[4]; int np;
    const ushort_t* W2p;                         // chain==2 second GEMM W
    const float* b1; const float* b2;
    int relu1, relu2;
    int chain;                                   // 1..2
    const float* rowmask; const float* cvec;     // optional rank-1 term
};

__global__ __launch_bounds__(512) void fgemm_kernel(
    FArgs fa, int M, ushort_t* __restrict__ out, int ldc) {
    __shared__ __align__(16) ushort_t Tlds[8192];          // 16 KB
    __shared__ __align__(16) ushort_t Wlds[16384];         // 32 KB

    int rowbase = blockIdx.x * 64;
    int colbase = blockIdx.y * 128;
    int tid = threadIdx.x;
    int lane = tid & 63, w = tid >> 6;           // 8 waves
    int wr3 = w & 3, wc2 = w >> 2;
    int lr = lane & 15, rq = (lane >> 4) * 4;

    f32x4 acc[4];
#pragma unroll
    for (int j = 0; j < 4; ++j) acc[j] = (f32x4){0.f, 0.f, 0.f, 0.f};

    u32x4 w2a = (u32x4){0u,0u,0u,0u}, w2b = w2a, w2c = w2a, w2d = w2a;

    for (int q = 0; q < fa.np; ++q) {
        const ushort_t* A = fa.p[q].A;
        const ushort_t* Wp = fa.p[q].Wp;
        int lda = fa.p[q].lda, K = fa.p[q].K;
        int nch = K >> 5;

        // async stage W slab: nch*512 uint4s, lane-contiguous
        {
            const ushort_t* wsrc = &Wp[((size_t)(colbase >> 4) * nch) * 512];
            for (int j = 0; j < nch; ++j) {
                int i = w * 64 + j * 512;        // wave-uniform uint4 base
                gload_lds16(wsrc + (size_t)(i + lane) * 8, &Wlds[i * 8]);
            }
        }
        // async stage A tile: subtile (c, rgrp) per wave-iteration, 16B/lane
        for (int s = w; s < nch * 4; s += 8) {
            int c = s >> 2, rgrp = s & 3;
            int gr = rowbase + rgrp * 16 + lr;
            int gcol = c * 32 + (lane >> 4) * 8;
            if (gr < M)
                gload_lds16(&A[(size_t)gr * lda + gcol], &Tlds[c * 2048 + rgrp * 512]);
        }
        // prefetch chain W2 into static registers (latency hides under GEMM1)
        if (q == 0 && fa.chain >= 2) {
            const u32x4* w2src = (const u32x4*)fa.W2p;
            w2a = w2src[tid];
            w2b = w2src[tid + 512];
            w2c = w2src[tid + 1024];
            w2d = w2src[tid + 1536];
        }
        __syncthreads();
        int cgl0 = wc2 * 4;
        for (int c = 0; c < nch; ++c) {
            bf16x8 af = *(const bf16x8*)&Tlds[c * 2048 + wr3 * 512 + lane * 8];
            bf16x8 bfr[4];
#pragma unroll
            for (int j = 0; j < 4; ++j)
                bfr[j] = *(const bf16x8*)&Wlds[(((cgl0 + j) * nch) + c) * 512 + lane * 8];
#pragma unroll
            for (int j = 0; j < 4; ++j)
                acc[j] = __builtin_amdgcn_mfma_f32_16x16x32_bf16(af, bfr[j], acc[j], 0, 0, 0);
        }
        __syncthreads();
    }

    if (fa.chain >= 2) {
        // W2 from registers -> LDS (no global latency here)
        ((u32x4*)Wlds)[tid] = w2a;
        ((u32x4*)Wlds)[tid + 512] = w2b;
        ((u32x4*)Wlds)[tid + 1024] = w2c;
        ((u32x4*)Wlds)[tid + 1536] = w2d;
        // epilogue of GEMM1 -> Tlds in fragment layout (A2[row][k=colj])
#pragma unroll
        for (int j = 0; j < 4; ++j) {
            int colj = wc2 * 64 + j * 16 + lr;
            float bv = fa.b1[colj];
            int kk = colj & 31;
            int cof = (colj >> 5) * 2048 + ((((kk >> 3) << 4)) << 3) + (kk & 7);
#pragma unroll
            for (int t = 0; t < 4; ++t) {
                int row = wr3 * 16 + rq + t;
                float v = acc[j][t] + bv;
                if (fa.relu1) v = fmaxf(v, 0.f);
                Tlds[cof + wr3 * 512 + ((row & 15) << 3)] = f2b(v);
            }
            acc[j] = (f32x4){0.f, 0.f, 0.f, 0.f};
        }
        __syncthreads();
        int cgl0 = wc2 * 4;
        for (int c = 0; c < 4; ++c) {
            bf16x8 af = *(const bf16x8*)&Tlds[c * 2048 + wr3 * 512 + lane * 8];
            bf16x8 bfr[4];
#pragma unroll
            for (int j = 0; j < 4; ++j)
                bfr[j] = *(const bf16x8*)&Wlds[((cgl0 + j) * 4 + c) * 512 + lane * 8];
#pragma unroll
            for (int j = 0; j < 4; ++j)
                acc[j] = __builtin_amdgcn_mfma_f32_16x16x32_bf16(af, bfr[j], acc[j], 0, 0, 0);
        }
        __syncthreads();
    }

    const float* bf_ = (fa.chain == 1) ? fa.b1 : fa.b2;
    int reluf = (fa.chain == 1) ? fa.relu1 : fa.relu2;
    float rm[4];
#pragma unroll
    for (int t = 0; t < 4; ++t) {
        int gr = rowbase + wr3 * 16 + rq + t;
        rm[t] = (fa.cvec && gr < M) ? fa.rowmask[gr] : 0.f;
    }
#pragma unroll
    for (int j = 0; j < 4; ++j) {
        int colj = wc2 * 64 + j * 16 + lr;
        float bv = bf_[colbase + colj];
        float cv = fa.cvec ? fa.cvec[colbase + colj] : 0.f;
#pragma unroll
        for (int t = 0; t < 4; ++t) {
            int row = wr3 * 16 + rq + t;
            float v = acc[j][t] + bv + rm[t] * cv;
            if (reluf) v = fmaxf(v, 0.f);
            Tlds[row * 128 + colj] = f2b(v);
        }
    }
    __syncthreads();
    for (int u = tid; u < 1024; u += 512) {
        int row = u >> 4, seg = u & 15;
        int gr = rowbase + row;
        if (gr < M)
            *(u32x4*)&out[(size_t)gr * ldc + colbase + seg * 8] =
                *(const u32x4*)&Tlds[row * 128 + seg * 8];
    }
}

// ---------------------------------------------------------------------------
// s0 GEMM + in-register projection (separate kernel, codegen-isolated).
// Epilogue: per-row dots onto pwl/pwr, shfl_xor reduce over lr lanes, then
// ONE coalesced float4 partial store per (yblock, wc2-half, row) -- 4 slices.
// ---------------------------------------------------------------------------
struct PArgs {
    GPass p[4];
    const float* b1;
    const float* rowmask; const float* cvec;
    const float* pwl; const float* pwr;
    float4* partials;                            // [4][N] float4 per row
};

__global__ __launch_bounds__(512) void fgemm_proj_kernel(PArgs fa, int M) {
    __shared__ __align__(16) ushort_t Tlds[8192];          // 16 KB
    __shared__ __align__(16) ushort_t Wlds[16384];         // 32 KB

    int rowbase = blockIdx.x * 64;
    int colbase = blockIdx.y * 128;
    int tid = threadIdx.x;
    int lane = tid & 63, w = tid >> 6;
    int wr3 = w & 3, wc2 = w >> 2;
    int lr = lane & 15, rq = (lane >> 4) * 4;

    f32x4 acc[4];
#pragma unroll
    for (int j = 0; j < 4; ++j) acc[j] = (f32x4){0.f, 0.f, 0.f, 0.f};

    for (int q = 0; q < 4; ++q) {
        const ushort_t* A = fa.p[q].A;
        const ushort_t* Wp = fa.p[q].Wp;
        int lda = fa.p[q].lda, K = fa.p[q].K;
        int nch = K >> 5;
        {
            const ushort_t* wsrc = &Wp[((size_t)(colbase >> 4) * nch) * 512];
            for (int j = 0; j < nch; ++j) {
                int i = w * 64 + j * 512;
                gload_lds16(wsrc + (size_t)(i + lane) * 8, &Wlds[i * 8]);
            }
        }
        for (int s = w; s < nch * 4; s += 8) {
            int c = s >> 2, rgrp = s & 3;
            int gr = rowbase + rgrp * 16 + lr;
            int gcol = c * 32 + (lane >> 4) * 8;
            if (gr < M)
                gload_lds16(&A[(size_t)gr * lda + gcol], &Tlds[c * 2048 + rgrp * 512]);
        }
        __syncthreads();
        int cgl0 = wc2 * 4;
        for (int c = 0; c < nch; ++c) {
            bf16x8 af = *(const bf16x8*)&Tlds[c * 2048 + wr3 * 512 + lane * 8];
            bf16x8 bfr[4];
#pragma unroll
            for (int j = 0; j < 4; ++j)
                bfr[j] = *(const bf16x8*)&Wlds[(((cgl0 + j) * nch) + c) * 512 + lane * 8];
#pragma unroll
            for (int j = 0; j < 4; ++j)
                acc[j] = __builtin_amdgcn_mfma_f32_16x16x32_bf16(af, bfr[j], acc[j], 0, 0, 0);
        }
        __syncthreads();
    }

    float rm[4];
#pragma unroll
    for (int t = 0; t < 4; ++t) {
        int gr = rowbase + wr3 * 16 + rq + t;
        rm[t] = (gr < M) ? fa.rowmask[gr] : 0.f;
    }
    float part[4][4];
#pragma unroll
    for (int t = 0; t < 4; ++t)
#pragma unroll
        for (int k = 0; k < 4; ++k) part[t][k] = 0.f;
#pragma unroll
    for (int j = 0; j < 4; ++j) {
        int c = colbase + wc2 * 64 + j * 16 + lr;
        float bv = fa.b1[c];
        float cv = fa.cvec[c];
        float wl0 = fa.pwl[2 * c], wl1 = fa.pwl[2 * c + 1];
        float wr0 = fa.pwr[2 * c], wr1 = fa.pwr[2 * c + 1];
#pragma unroll
        for (int t = 0; t < 4; ++t) {
            float v = fmaxf(acc[j][t] + bv + rm[t] * cv, 0.f);
            part[t][0] += v * wl0;
            part[t][1] += v * wl1;
            part[t][2] += v * wr0;
            part[t][3] += v * wr1;
        }
    }
#pragma unroll
    for (int t = 0; t < 4; ++t)
#pragma unroll
        for (int k = 0; k < 4; ++k) {
            float s = part[t][k];
            s += __shfl_xor(s, 1);
            s += __shfl_xor(s, 2);
            s += __shfl_xor(s, 4);
            s += __shfl_xor(s, 8);
            part[t][k] = s;
        }
    if (lr == 0) {
        int slice = blockIdx.y * 2 + wc2;        // 4 reduction slices
#pragma unroll
        for (int t = 0; t < 4; ++t) {
            int gr = rowbase + wr3 * 16 + rq + t;
            if (gr < M)
                fa.partials[(size_t)slice * M + gr] =
                    make_float4(part[t][0], part[t][1], part[t][2], part[t][3]);
        }
    }
}

// combine the four (yblock, col-half) partials into zl (left) and z (right)
__global__ void combine_kernel(const float4* __restrict__ partials, int Nn,
                               float2* __restrict__ zl, float2* __restrict__ z) {
    int i = blockIdx.x * blockDim.x + threadIdx.x;
    if (i >= Nn) return;
    float4 a = partials[i];
    float4 b = partials[(size_t)Nn + i];
    float4 c = partials[(size_t)2 * Nn + i];
    float4 d = partials[(size_t)3 * Nn + i];
    zl[i] = make_float2((a.x + b.x) + (c.x + d.x), (a.y + b.y) + (c.y + d.y));
    z[i] = make_float2((a.z + b.z) + (c.z + d.z), (a.w + b.w) + (c.w + d.w));
}

// out[i] = zl[i] + invdeg[i] * sum_nbr z[j] + b ; one thread per node
__global__ void aggz_kernel(const float2* __restrict__ z, const float2* __restrict__ zl,
                            const int* __restrict__ rowptr, const int* __restrict__ col,
                            const float* __restrict__ invdeg, const float* __restrict__ b,
                            float* __restrict__ out, int Nn) {
    int i = blockIdx.x * blockDim.x + threadIdx.x;
    if (i >= Nn) return;
    float s0 = 0.f, s1 = 0.f;
    int p = rowptr[i], p1 = rowptr[i + 1];
    for (; p + 4 <= p1; p += 4) {
        float2 a = z[col[p]], c = z[col[p + 1]], d = z[col[p + 2]], e = z[col[p + 3]];
        s0 += (a.x + c.x) + (d.x + e.x);
        s1 += (a.y + c.y) + (d.y + e.y);
    }
    for (; p < p1; ++p) {
        float2 a = z[col[p]];
        s0 += a.x; s1 += a.y;
    }
    float inv = invdeg[i];
    float2 l = zl[i];
    out[(size_t)i * 2 + 0] = l.x + inv * s0 + b[0];
    out[(size_t)i * 2 + 1] = l.y + inv * s1 + b[1];
}

extern "C" void kernel_launch(void* const* d_in, const int* in_sizes, int n_in,
                              void* d_out, int out_size, void* d_ws, size_t ws_size,
                              hipStream_t stream) {
    const float* x      = (const float*)d_in[0];
    const int*   ei     = (const int*)d_in[1];
    const float* g_w1[3] = {(const float*)d_in[2], (const float*)d_in[6],  (const float*)d_in[10]};
    const float* g_b1[3] = {(const float*)d_in[3], (const float*)d_in[7],  (const float*)d_in[11]};
    const float* g_w2[3] = {(const float*)d_in[4], (const float*)d_in[8],  (const float*)d_in[12]};
    const float* g_b2[3] = {(const float*)d_in[5], (const float*)d_in[9],  (const float*)d_in[13]};
    const float* gout_w = (const float*)d_in[14];
    const float* gout_b = (const float*)d_in[15];
    const float* s0_wl  = (const float*)d_in[16];
    const float* s0_wr  = (const float*)d_in[17];
    const float* s0_b   = (const float*)d_in[18];
    const float* s1_wl  = (const float*)d_in[19];
    const float* s1_wr  = (const float*)d_in[20];
    const float* s1_b   = (const float*)d_in[21];
    float* out = (float*)d_out;

    const int N = in_sizes[0] / 64;
    const int E = in_sizes[1] / 2;

    char* ws = (char*)d_ws;
    size_t o = 0;
    auto take = [&](size_t bytes) -> char* {
        char* p = ws + o;
        o = (o + bytes + 255) & ~(size_t)255;
        return p;
    };
    ushort_t* xb     = (ushort_t*)take((size_t)N * 64 * 2);
    ushort_t* bA     = (ushort_t*)take((size_t)N * 128 * 2);
    ushort_t* bB     = (ushort_t*)take((size_t)N * 128 * 2);
    ushort_t* bC     = (ushort_t*)take((size_t)N * 128 * 2);
    ushort_t* aggxb  = (ushort_t*)take((size_t)N * 64 * 2);
    ushort_t* agggb  = (ushort_t*)take((size_t)N * 128 * 2);
    float2*   zlb    = (float2*)take((size_t)N * 2 * 4);
    float2*   zb     = (float2*)take((size_t)N * 2 * 4);
    float4*   partials = (float4*)take((size_t)N * 4 * 16);
    float* Flbuf = (float*)take(128 * 256 * 4);
    float* Frbuf = (float*)take(128 * 256 * 4);
    float* bias2 = (float*)take(256 * 4);
    float* cvecb = (float*)take(256 * 4);
    ushort_t* w1t0 = (ushort_t*)take(128 * 32 * 2);
    ushort_t* w2t0 = (ushort_t*)take(128 * 128 * 2);
    ushort_t* w1t1 = (ushort_t*)take(128 * 128 * 2);
    ushort_t* w2t1 = (ushort_t*)take(128 * 128 * 2);
    ushort_t* w1t2 = (ushort_t*)take(128 * 128 * 2);
    ushort_t* w2t2 = (ushort_t*)take(128 * 128 * 2);
    ushort_t* wltop = (ushort_t*)take(256 * 64 * 2);
    ushort_t* wglp  = (ushort_t*)take(256 * 128 * 2);
    ushort_t* wrtop = (ushort_t*)take(256 * 64 * 2);
    ushort_t* wgrp  = (ushort_t*)take(256 * 128 * 2);
    unsigned* stage  = (unsigned*)take((size_t)E * 4);
    int*   colI   = (int*)take((size_t)E * 4);
    int*   rowptr = (int*)take((size_t)(N + 1) * 4);
    int*   deg    = (int*)take((size_t)N * 4);
    float* invdeg = (float*)take((size_t)N * 4);
    float* maskb  = (float*)take((size_t)N * 4);
    int*   blocksum = (int*)take(256 * 4);
    int*   blockoff = (int*)take(256 * 4);
    int*   bucket_cursor = (int*)take(512 * 4);
    int*   flag   = (int*)take(4);

    hipMemsetAsync(deg, 0, (size_t)N * 4, stream);
    hipMemsetAsync(flag, 1, 4, stream);

    const int TB = 256;
    const int nb = (N + 2047) / 2048;
    const int NBKT = (N + 255) >> 8;

    // --- CSR by dst: deg -> scan -> binned two-phase build ---
    detect_kernel<<<4, TB, 0, stream>>>(ei, 1024, flag);
    deg_kernel<<<(E + TB - 1) / TB, TB, 0, stream>>>(ei, E, flag, deg);
    scanA_kernel<<<nb, 256, 0, stream>>>(deg, N, rowptr, blocksum);
    scanB_kernel<<<1, 256, 0, stream>>>(blocksum, nb, blockoff, rowptr, N);
    scanC_kernel<<<(N + TB - 1) / TB, TB, 0, stream>>>(deg, N, blockoff, rowptr, invdeg, maskb, bucket_cursor);
    binA_kernel<<<(E + 4095) / 4096, 256, 0, stream>>>(ei, E, flag, bucket_cursor, stage);
    binB_kernel<<<NBKT, 256, 0, stream>>>(stage, rowptr, N, colI);

    // --- gout fold (fp32) + weight convert/pack ---
    foldw_kernel<<<128, 256, 0, stream>>>(gout_w, gout_b, s0_wl, s0_wr, s0_b,
                                          Flbuf, Frbuf, bias2, cvecb);
    WtArgs wa;
    const float* wsrc[10] = {g_w1[0], g_w2[0], g_w1[1], g_w2[1], g_w1[2], g_w2[2],
                             s0_wl, Flbuf, s0_wr, Frbuf};
    ushort_t* wdst[10]    = {w1t0, w2t0, w1t1, w2t1, w1t2, w2t2,
                             wltop, wglp, wrtop, wgrp};
    int wk[10]  = {32, 128, 128, 128, 128, 128, 64, 128, 64, 128};
    int wl2[10] = {5, 7, 7, 7, 7, 7, 6, 7, 6, 7};
    int wn[10]  = {128, 128, 128, 128, 128, 128, 256, 256, 256, 256};
    int base = 0;
    for (int i = 0; i < 10; ++i) {
        wa.d[i].src = wsrc[i]; wa.d[i].dst = wdst[i];
        wa.d[i].lk2 = wl2[i]; wa.d[i].K = wk[i]; wa.d[i].N = wn[i]; wa.d[i].base = base;
        base += wk[i] * wn[i];
    }
    wa.total = base;
    wtconv_kernel<<<(base + TB - 1) / TB, TB, 0, stream>>>(wa);

    // --- x -> bf16 ---
    xconv_kernel<<<((N * 16) + TB - 1) / TB, TB, 0, stream>>>(x, xb, N * 16);

    const int AGG_GRID = (N + 3) / 4;
    const int GX = (N + 63) / 64;

    // merged x-gather: bB = GIN-0 input (32-wide), aggxb = mean1-x (64-wide)
    aggdual_kernel<<<AGG_GRID, 256, 0, stream>>>(xb, rowptr, colI, invdeg, bB, aggxb, N);

    // --- GIN layer 0 (chain=2): bB -> h1 = bA ---
    {
        FArgs fa = {};
        fa.p[0] = {bB, w1t0, 32, 32};
        fa.np = 1;
        fa.W2p = w2t0;
        fa.b1 = g_b1[0]; fa.b2 = g_b2[0];
        fa.relu1 = 1; fa.relu2 = 1;
        fa.chain = 2;
        fgemm_kernel<<<dim3(GX, 1), 512, 0, stream>>>(fa, N, bA, 128);
    }

    // --- GIN layer 1: bA -> agg bB -> h2 = bC ---
    aggb_kernel<2, 0><<<AGG_GRID, 256, 0, stream>>>(bA, 128, rowptr, colI, invdeg, bB, 128, N, 64);
    {
        FArgs fa = {};
        fa.p[0] = {bB, w1t1, 128, 128};
        fa.np = 1;
        fa.W2p = w2t1;
        fa.b1 = g_b1[1]; fa.b2 = g_b2[1];
        fa.relu1 = 1; fa.relu2 = 1;
        fa.chain = 2;
        fgemm_kernel<<<dim3(GX, 1), 512, 0, stream>>>(fa, N, bC, 128);
    }

    // --- GIN layer 2 (chain=2): bC -> agg bB -> h3 = bA ---
    aggb_kernel<2, 0><<<AGG_GRID, 256, 0, stream>>>(bC, 128, rowptr, colI, invdeg, bB, 128, N, 64);
    {
        FArgs fa = {};
        fa.p[0] = {bB, w1t2, 128, 128};
        fa.np = 1;
        fa.W2p = w2t2;
        fa.b1 = g_b1[2]; fa.b2 = g_b2[2];
        fa.relu1 = 1; fa.relu2 = 1;
        fa.chain = 2;
        fgemm_kernel<<<dim3(GX, 1), 512, 0, stream>>>(fa, N, bA, 128);
    }

    // mean-agg(h3) (gout folded into s0 weights)
    aggb_kernel<2, 1><<<AGG_GRID, 256, 0, stream>>>(bA, 128, rowptr, colI, invdeg, agggb, 128, N, 64);

    // s0 = relu(x@wltop + h3@Fl + aggx@wrtop + aggh3@Fr + bias2 + mask.cvec),
    // fused with projection onto s1_wl/s1_wr; partial float4 per (y,wc2,row)
    {
        PArgs fa = {};
        fa.p[0] = {xb, wltop, 64, 64};
        fa.p[1] = {bA, wglp, 128, 128};
        fa.p[2] = {aggxb, wrtop, 64, 64};
        fa.p[3] = {agggb, wgrp, 128, 128};
        fa.b1 = bias2;
        fa.rowmask = maskb; fa.cvec = cvecb;
        fa.pwl = s1_wl; fa.pwr = s1_wr;
        fa.partials = partials;
        fgemm_proj_kernel<<<dim3(GX, 2), 512, 0, stream>>>(fa, N);
    }

    // combine four partial slices -> zl, z
    combine_kernel<<<(N + TB - 1) / TB, TB, 0, stream>>>(partials, N, zlb, zb);

    // out = zl + invdeg * agg(z) + b
    aggz_kernel<<<(N + TB - 1) / TB, TB, 0, stream>>>(zb, zlb, rowptr, colI, invdeg, s1_b, out, N);
}